// Round 1
// baseline (2102.962 us; speedup 1.0000x reference)
//
#include <hip/hip_runtime.h>
#include <math.h>

#define N_ROWS 8192
#define DIM 512
#define HID 1024

__device__ __forceinline__ bool dj_less(float d1, int j1, float d2, int j2) {
  return (d1 < d2) || (d1 == d2 && j1 < j2);
}

// ---------------- row squared norms ----------------
__global__ __launch_bounds__(64) void rowsq_kernel(const float* __restrict__ x,
                                                   float* __restrict__ sq) {
  int row = blockIdx.x;
  int t = threadIdx.x;
  const float* xr = x + (size_t)row * DIM;
  float4 v1 = *reinterpret_cast<const float4*>(&xr[t * 4]);
  float4 v2 = *reinterpret_cast<const float4*>(&xr[256 + t * 4]);
  float s = v1.x * v1.x + v1.y * v1.y + v1.z * v1.z + v1.w * v1.w +
            v2.x * v2.x + v2.y * v2.y + v2.z * v2.z + v2.w * v2.w;
  for (int off = 32; off > 0; off >>= 1) s += __shfl_down(s, off);
  if (t == 0) sq[row] = s;
}

// ---------------- fused distance + per-row top4 (partial over j-split) ----------------
// grid (128 row-tiles, 4 j-splits), block 256.  Tile 64x64, 4x4 per thread.
__global__ __launch_bounds__(256) void dist_top4_kernel(const float* __restrict__ x,
                                                        const float* __restrict__ sq,
                                                        float* __restrict__ cand_d,
                                                        int* __restrict__ cand_j) {
  __shared__ float smemF[8192];        // tiles: A k-major [32][65] @0, B @2080 ; merge: 32KB
  int* smemI = (int*)smemF;
  const int tid = threadIdx.x;
  const int tx = tid & 15, ty = tid >> 4;
  const int row0 = blockIdx.x * 64;
  const int js = blockIdx.y;

  float bd[4][4];
  int bj[4][4];
#pragma unroll
  for (int m = 0; m < 4; ++m)
#pragma unroll
    for (int p = 0; p < 4; ++p) { bd[m][p] = 3.0e38f; bj[m][p] = 0x7fffffff; }

  for (int jt = 0; jt < 32; ++jt) {
    const int col0 = js * 2048 + jt * 64;
    float acc[4][4];
#pragma unroll
    for (int m = 0; m < 4; ++m)
#pragma unroll
      for (int n = 0; n < 4; ++n) acc[m][n] = 0.0f;

    for (int kt = 0; kt < DIM; kt += 32) {
#pragma unroll
      for (int q = 0; q < 2; ++q) {
        int idx = tid * 2 + q;
        int r = idx >> 3;
        int kk = (idx & 7) << 2;
        float4 av = *reinterpret_cast<const float4*>(&x[(size_t)(row0 + r) * DIM + kt + kk]);
        smemF[(kk + 0) * 65 + r] = av.x;
        smemF[(kk + 1) * 65 + r] = av.y;
        smemF[(kk + 2) * 65 + r] = av.z;
        smemF[(kk + 3) * 65 + r] = av.w;
        float4 bv = *reinterpret_cast<const float4*>(&x[(size_t)(col0 + r) * DIM + kt + kk]);
        smemF[2080 + (kk + 0) * 65 + r] = bv.x;
        smemF[2080 + (kk + 1) * 65 + r] = bv.y;
        smemF[2080 + (kk + 2) * 65 + r] = bv.z;
        smemF[2080 + (kk + 3) * 65 + r] = bv.w;
      }
      __syncthreads();
#pragma unroll
      for (int k = 0; k < 32; ++k) {
        float a0 = smemF[k * 65 + ty];
        float a1 = smemF[k * 65 + ty + 16];
        float a2 = smemF[k * 65 + ty + 32];
        float a3 = smemF[k * 65 + ty + 48];
        float b0 = smemF[2080 + k * 65 + tx];
        float b1 = smemF[2080 + k * 65 + tx + 16];
        float b2 = smemF[2080 + k * 65 + tx + 32];
        float b3 = smemF[2080 + k * 65 + tx + 48];
        acc[0][0] = fmaf(a0, b0, acc[0][0]);
        acc[0][1] = fmaf(a0, b1, acc[0][1]);
        acc[0][2] = fmaf(a0, b2, acc[0][2]);
        acc[0][3] = fmaf(a0, b3, acc[0][3]);
        acc[1][0] = fmaf(a1, b0, acc[1][0]);
        acc[1][1] = fmaf(a1, b1, acc[1][1]);
        acc[1][2] = fmaf(a1, b2, acc[1][2]);
        acc[1][3] = fmaf(a1, b3, acc[1][3]);
        acc[2][0] = fmaf(a2, b0, acc[2][0]);
        acc[2][1] = fmaf(a2, b1, acc[2][1]);
        acc[2][2] = fmaf(a2, b2, acc[2][2]);
        acc[2][3] = fmaf(a2, b3, acc[2][3]);
        acc[3][0] = fmaf(a3, b0, acc[3][0]);
        acc[3][1] = fmaf(a3, b1, acc[3][1]);
        acc[3][2] = fmaf(a3, b2, acc[3][2]);
        acc[3][3] = fmaf(a3, b3, acc[3][3]);
      }
      __syncthreads();
    }

    // epilogue: distances + top4 insert (j ascending within thread -> stable ties)
    float sqj[4];
#pragma unroll
    for (int n = 0; n < 4; ++n) sqj[n] = sq[col0 + tx + 16 * n];
#pragma unroll
    for (int m = 0; m < 4; ++m) {
      float sqi = sq[row0 + ty + 16 * m];
#pragma unroll
      for (int n = 0; n < 4; ++n) {
        int j = col0 + tx + 16 * n;
        float d = (sqi + sqj[n]) - 2.0f * acc[m][n];
        if (dj_less(d, j, bd[m][3], bj[m][3])) {
          bd[m][3] = d; bj[m][3] = j;
#pragma unroll
          for (int p = 3; p > 0; --p) {
            if (dj_less(bd[m][p], bj[m][p], bd[m][p - 1], bj[m][p - 1])) {
              float td = bd[m][p]; bd[m][p] = bd[m][p - 1]; bd[m][p - 1] = td;
              int tj = bj[m][p]; bj[m][p] = bj[m][p - 1]; bj[m][p - 1] = tj;
            }
          }
        }
      }
    }
  }

  __syncthreads();
  // stash candidates: d at smemF[s*64 + r], j at smemI[4096 + s*64 + r]  (conflict-free scan)
#pragma unroll
  for (int m = 0; m < 4; ++m) {
    int r = ty + 16 * m;
#pragma unroll
    for (int p = 0; p < 4; ++p) {
      int s = tx * 4 + p;
      smemF[s * 64 + r] = bd[m][p];
      smemI[4096 + s * 64 + r] = bj[m][p];
    }
  }
  __syncthreads();
  if (tid < 64) {
    int row = row0 + tid;
    for (int p = 0; p < 4; ++p) {
      float bestd = 3.0e38f;
      int bestj = 0x7fffffff;
      int bests = 0;
      for (int s = 0; s < 64; ++s) {
        float dv = smemF[s * 64 + tid];
        int jv = smemI[4096 + s * 64 + tid];
        if (dj_less(dv, jv, bestd, bestj)) { bestd = dv; bestj = jv; bests = s; }
      }
      smemF[bests * 64 + tid] = 3.0e38f;
      cand_d[(size_t)row * 16 + js * 4 + p] = bestd;
      cand_j[(size_t)row * 16 + js * 4 + p] = bestj;
    }
  }
}

// ---------------- merge 4 j-split candidate lists -> final top4 + index outputs ----------------
__global__ __launch_bounds__(256) void merge_final_kernel(const float* __restrict__ cand_d,
                                                          const int* __restrict__ cand_j,
                                                          int* __restrict__ subsets,
                                                          float* __restrict__ orows,
                                                          float* __restrict__ osubs) {
  int row = blockIdx.x * 256 + threadIdx.x;
  float cd[16];
  int cj[16];
#pragma unroll
  for (int s = 0; s < 16; ++s) {
    cd[s] = cand_d[(size_t)row * 16 + s];
    cj[s] = cand_j[(size_t)row * 16 + s];
  }
#pragma unroll
  for (int i = 0; i < 16; ++i) {
    int rank = 0;
#pragma unroll
    for (int k = 0; k < 16; ++k)
      rank += dj_less(cd[k], cj[k], cd[i], cj[i]) ? 1 : 0;
    if (rank < 4) {
      subsets[row * 4 + rank] = cj[i];
      orows[row * 4 + rank] = (float)row;
      osubs[row * 4 + rank] = (float)cj[i];
    }
  }
}

// ---------------- gather + mean/max pool -> h0 ----------------
__global__ __launch_bounds__(128) void pool_kernel(const float* __restrict__ x,
                                                   const int* __restrict__ subsets,
                                                   float* __restrict__ h0) {
  int i = blockIdx.x, t = threadIdx.x;
  int s0 = subsets[i * 4 + 0];
  int s1 = subsets[i * 4 + 1];
  int s2 = subsets[i * 4 + 2];
  int s3 = subsets[i * 4 + 3];
  int c = t * 4;
  float4 z0 = *reinterpret_cast<const float4*>(&x[(size_t)s0 * DIM + c]);
  float4 z1 = *reinterpret_cast<const float4*>(&x[(size_t)s1 * DIM + c]);
  float4 z2 = *reinterpret_cast<const float4*>(&x[(size_t)s2 * DIM + c]);
  float4 z3 = *reinterpret_cast<const float4*>(&x[(size_t)s3 * DIM + c]);
  float4 mu, mx;
  mu.x = (z0.x + z1.x + z2.x + z3.x) * 0.25f;
  mu.y = (z0.y + z1.y + z2.y + z3.y) * 0.25f;
  mu.z = (z0.z + z1.z + z2.z + z3.z) * 0.25f;
  mu.w = (z0.w + z1.w + z2.w + z3.w) * 0.25f;
  mx.x = fmaxf(fmaxf(z0.x, z1.x), fmaxf(z2.x, z3.x));
  mx.y = fmaxf(fmaxf(z0.y, z1.y), fmaxf(z2.y, z3.y));
  mx.z = fmaxf(fmaxf(z0.z, z1.z), fmaxf(z2.z, z3.z));
  mx.w = fmaxf(fmaxf(z0.w, z1.w), fmaxf(z2.w, z3.w));
  *reinterpret_cast<float4*>(&h0[(size_t)i * HID + c]) = mu;
  *reinterpret_cast<float4*>(&h0[(size_t)i * HID + DIM + c]) = mx;
}

// ---------------- fp32 GEMM: out = act(A @ W^T + bias), A (8192xK), W (1024xK) ----------------
__global__ __launch_bounds__(256) void gemm_bias_act_kernel(const float* __restrict__ A,
                                                            const float* __restrict__ W,
                                                            const float* __restrict__ bias,
                                                            float* __restrict__ out,
                                                            int K, int act) {
  __shared__ float As[32][65];
  __shared__ float Bs[32][65];
  const int tid = threadIdx.x;
  const int tx = tid & 15, ty = tid >> 4;
  const int row0 = blockIdx.x * 64, col0 = blockIdx.y * 64;
  float acc[4][4];
#pragma unroll
  for (int m = 0; m < 4; ++m)
#pragma unroll
    for (int n = 0; n < 4; ++n) acc[m][n] = 0.0f;

  for (int kt = 0; kt < K; kt += 32) {
#pragma unroll
    for (int q = 0; q < 2; ++q) {
      int idx = tid * 2 + q;
      int r = idx >> 3;
      int kk = (idx & 7) << 2;
      float4 av = *reinterpret_cast<const float4*>(&A[(size_t)(row0 + r) * K + kt + kk]);
      As[kk + 0][r] = av.x;
      As[kk + 1][r] = av.y;
      As[kk + 2][r] = av.z;
      As[kk + 3][r] = av.w;
      float4 bv = *reinterpret_cast<const float4*>(&W[(size_t)(col0 + r) * K + kt + kk]);
      Bs[kk + 0][r] = bv.x;
      Bs[kk + 1][r] = bv.y;
      Bs[kk + 2][r] = bv.z;
      Bs[kk + 3][r] = bv.w;
    }
    __syncthreads();
#pragma unroll
    for (int k = 0; k < 32; ++k) {
      float a0 = As[k][ty], a1 = As[k][ty + 16], a2 = As[k][ty + 32], a3 = As[k][ty + 48];
      float b0 = Bs[k][tx], b1 = Bs[k][tx + 16], b2 = Bs[k][tx + 32], b3 = Bs[k][tx + 48];
      acc[0][0] = fmaf(a0, b0, acc[0][0]);
      acc[0][1] = fmaf(a0, b1, acc[0][1]);
      acc[0][2] = fmaf(a0, b2, acc[0][2]);
      acc[0][3] = fmaf(a0, b3, acc[0][3]);
      acc[1][0] = fmaf(a1, b0, acc[1][0]);
      acc[1][1] = fmaf(a1, b1, acc[1][1]);
      acc[1][2] = fmaf(a1, b2, acc[1][2]);
      acc[1][3] = fmaf(a1, b3, acc[1][3]);
      acc[2][0] = fmaf(a2, b0, acc[2][0]);
      acc[2][1] = fmaf(a2, b1, acc[2][1]);
      acc[2][2] = fmaf(a2, b2, acc[2][2]);
      acc[2][3] = fmaf(a2, b3, acc[2][3]);
      acc[3][0] = fmaf(a3, b0, acc[3][0]);
      acc[3][1] = fmaf(a3, b1, acc[3][1]);
      acc[3][2] = fmaf(a3, b2, acc[3][2]);
      acc[3][3] = fmaf(a3, b3, acc[3][3]);
    }
    __syncthreads();
  }
#pragma unroll
  for (int m = 0; m < 4; ++m) {
    int rr = row0 + ty + 16 * m;
#pragma unroll
    for (int n = 0; n < 4; ++n) {
      int cc = col0 + tx + 16 * n;
      float v = acc[m][n] + bias[cc];
      if (act && v < 0.0f) v *= 0.01f;
      out[(size_t)rr * HID + cc] = v;
    }
  }
}

// ---------------- final elementwise + entropy partial sums ----------------
__global__ __launch_bounds__(256) void outgen_kernel(const float* __restrict__ x,
                                                     const float* __restrict__ h2,
                                                     const float* __restrict__ eps,
                                                     float* __restrict__ xout,
                                                     float* __restrict__ partials) {
  int tid = threadIdx.x;
  int gid = blockIdx.x * 256 + tid;
  size_t base = (size_t)gid * 4;
  int i = (int)(base >> 9);
  int c = (int)(base & 511);
  float4 xv = *reinterpret_cast<const float4*>(&x[base]);
  float4 ev = *reinterpret_cast<const float4*>(&eps[base]);
  float4 mu = *reinterpret_cast<const float4*>(&h2[(size_t)i * HID + c]);
  float4 hs = *reinterpret_cast<const float4*>(&h2[(size_t)i * HID + DIM + c]);
  float4 xo;
  xo.x = xv.x + mu.x + expf(0.5f * hs.x) * ev.x;
  xo.y = xv.y + mu.y + expf(0.5f * hs.y) * ev.y;
  xo.z = xv.z + mu.z + expf(0.5f * hs.z) * ev.z;
  xo.w = xv.w + mu.w + expf(0.5f * hs.w) * ev.w;
  *reinterpret_cast<float4*>(&xout[base]) = xo;
  float lsum = hs.x + hs.y + hs.z + hs.w;
  for (int off = 32; off > 0; off >>= 1) lsum += __shfl_down(lsum, off);
  __shared__ float red[4];
  if ((tid & 63) == 0) red[tid >> 6] = lsum;
  __syncthreads();
  if (tid == 0) partials[blockIdx.x] = red[0] + red[1] + red[2] + red[3];
}

__global__ __launch_bounds__(256) void entfin_kernel(const float* __restrict__ partials,
                                                     float* __restrict__ ent) {
  int t = threadIdx.x;
  float s = 0.0f;
  for (int q = 0; q < 16; ++q) s += partials[t + 256 * q];
  for (int off = 32; off > 0; off >>= 1) s += __shfl_down(s, off);
  __shared__ float red[4];
  if ((t & 63) == 0) red[t >> 6] = s;
  __syncthreads();
  if (t == 0)
    ent[0] = 0.5f + 0.9189385332046727f +
             0.5f * (red[0] + red[1] + red[2] + red[3]) / (8192.0f * 512.0f);
}

extern "C" void kernel_launch(void* const* d_in, const int* in_sizes, int n_in,
                              void* d_out, int out_size, void* d_ws, size_t ws_size,
                              hipStream_t stream) {
  const float* x = (const float*)d_in[0];
  const float* W1 = (const float*)d_in[1];
  const float* b1 = (const float*)d_in[2];
  const float* W2 = (const float*)d_in[3];
  const float* b2 = (const float*)d_in[4];
  const float* eps = (const float*)d_in[5];

  float* out = (float*)d_out;
  float* ws = (float*)d_ws;

  // workspace layout (floats)
  float* sq = ws;                         // 8192
  int* subsets = (int*)(ws + 8192);       // 32768 ints
  float* cand_d = ws + 40960;             // 8192*16
  int* cand_j = (int*)(ws + 172032);      // 8192*16 ints
  float* h0 = ws + 303104;                // 8192*1024
  float* h1 = ws + 8691712;               // 8192*1024
  float* h2 = h0;                         // reuse h0 after gemm1
  float* partials = ws + 17080320;        // 4096

  float* xout = out;
  float* ent = out + (size_t)N_ROWS * DIM;
  float* orows = ent + 1;
  float* osubs = orows + (size_t)N_ROWS * 4;

  rowsq_kernel<<<N_ROWS, 64, 0, stream>>>(x, sq);
  dist_top4_kernel<<<dim3(128, 4), 256, 0, stream>>>(x, sq, cand_d, cand_j);
  merge_final_kernel<<<32, 256, 0, stream>>>(cand_d, cand_j, subsets, orows, osubs);
  pool_kernel<<<N_ROWS, 128, 0, stream>>>(x, subsets, h0);
  gemm_bias_act_kernel<<<dim3(128, 16), 256, 0, stream>>>(h0, W1, b1, h1, HID, 1);
  gemm_bias_act_kernel<<<dim3(128, 16), 256, 0, stream>>>(h1, W2, b2, h2, HID, 0);
  outgen_kernel<<<4096, 256, 0, stream>>>(x, h2, eps, xout, partials);
  entfin_kernel<<<1, 256, 0, stream>>>(partials, ent);
}

// Round 2
// 942.040 us; speedup vs baseline: 2.2323x; 2.2323x over previous
//
#include <hip/hip_runtime.h>
#include <math.h>

#define N_ROWS 8192
#define DIM 512
#define HID 1024

typedef _Float16 f16x8 __attribute__((ext_vector_type(8)));
typedef _Float16 f16x4 __attribute__((ext_vector_type(4)));
typedef float f32x4 __attribute__((ext_vector_type(4)));

__device__ __forceinline__ bool dj_less(float d1, int j1, float d2, int j2) {
  return (d1 < d2) || (d1 == d2 && j1 < j2);
}

__device__ __forceinline__ void gload_lds16(const void* g, void* s) {
  __builtin_amdgcn_global_load_lds((const __attribute__((address_space(1))) void*)g,
                                   (__attribute__((address_space(3))) void*)s, 16, 0, 0);
}

#define S_SWZ(r) ((((r) & 3) ^ (((r) >> 2) & 3)))

// ---------------- row squared norms ----------------
__global__ __launch_bounds__(64) void rowsq_kernel(const float* __restrict__ x,
                                                   float* __restrict__ sq) {
  int row = blockIdx.x;
  int t = threadIdx.x;
  const float* xr = x + (size_t)row * DIM;
  float4 v1 = *reinterpret_cast<const float4*>(&xr[t * 4]);
  float4 v2 = *reinterpret_cast<const float4*>(&xr[256 + t * 4]);
  float s = v1.x * v1.x + v1.y * v1.y + v1.z * v1.z + v1.w * v1.w +
            v2.x * v2.x + v2.y * v2.y + v2.z * v2.z + v2.w * v2.w;
  for (int off = 32; off > 0; off >>= 1) s += __shfl_down(s, off);
  if (t == 0) sq[row] = s;
}

// ---------------- split fp32 -> f16 hi + scaled lo ----------------
__global__ __launch_bounds__(256) void split_kernel(const float* __restrict__ x,
                                                    _Float16* __restrict__ xhi,
                                                    _Float16* __restrict__ xlo) {
  int g = blockIdx.x * 256 + threadIdx.x;
  float4 v = reinterpret_cast<const float4*>(x)[g];
  _Float16 h0 = (_Float16)v.x, h1 = (_Float16)v.y, h2 = (_Float16)v.z, h3 = (_Float16)v.w;
  _Float16 l0 = (_Float16)((v.x - (float)h0) * 2048.0f);
  _Float16 l1 = (_Float16)((v.y - (float)h1) * 2048.0f);
  _Float16 l2 = (_Float16)((v.z - (float)h2) * 2048.0f);
  _Float16 l3 = (_Float16)((v.w - (float)h3) * 2048.0f);
  f16x4 hv = {h0, h1, h2, h3};
  f16x4 lv = {l0, l1, l2, l3};
  reinterpret_cast<f16x4*>(xhi)[g] = hv;
  reinterpret_cast<f16x4*>(xlo)[g] = lv;
}

// ---------------- MFMA distance + per-row top4 (partial over 8 j-splits) ----------------
// grid (64 row-tiles, 8 j-splits), block 256 (4 waves, 2x2).  Tile 128x128, BK=32.
__global__ __launch_bounds__(256, 2) void dist_top4_mfma(const _Float16* __restrict__ xhi,
                                                         const _Float16* __restrict__ xlo,
                                                         const float* __restrict__ sq,
                                                         float* __restrict__ cand_d,
                                                         int* __restrict__ cand_j) {
  // LDS: Ah[0,8K) Al[8K,16K) Bh[16K,24K) Bl[24K,32K) bytes ; D f32[64][132] at 32768
  __shared__ char smem[66560];
  float* Df = (float*)(smem + 32768);
  const int tid = threadIdx.x;
  const int lane = tid & 63;
  const int w = tid >> 6;
  const int wm = w >> 1, wn = w & 1;
  const int row0 = blockIdx.x * 128;
  const int js = blockIdx.y;

  // fragment read byte-offsets (within a tensor tile), swizzled
  int a_off[4], b_off[4];
#pragma unroll
  for (int m = 0; m < 4; ++m) {
    int r = wm * 64 + m * 16 + (lane & 15);
    a_off[m] = r * 64 + (((lane >> 4) ^ S_SWZ(r)) * 16);
  }
#pragma unroll
  for (int n = 0; n < 4; ++n) {
    int r = wn * 64 + n * 16 + (lane & 15);
    b_off[n] = r * 64 + (((lane >> 4) ^ S_SWZ(r)) * 16);
  }

  // staging addressing: half h covers chunk index i = h*256+tid ; r=i>>2, slot=i&3
  int goff[2], wb[2];
#pragma unroll
  for (int h = 0; h < 2; ++h) {
    int i = h * 256 + tid;
    int r = i >> 2, cs = i & 3;
    int c = cs ^ S_SWZ(r);
    goff[h] = r * 512 + c * 8;        // f16 elements
    wb[h] = h * 4096 + w * 1024;      // bytes, wave-uniform
  }

  const int sr = tid >> 2;  // scan row within phase (0..63)
  const int sc = tid & 3;   // scan col offset

  float bd[2][4];
  int bj[2][4];
#pragma unroll
  for (int p = 0; p < 2; ++p)
#pragma unroll
    for (int k = 0; k < 4; ++k) { bd[p][k] = 3.0e38f; bj[p][k] = 0x7fffffff; }

  const _Float16* arow_h = xhi + (size_t)row0 * DIM;
  const _Float16* arow_l = xlo + (size_t)row0 * DIM;

#pragma unroll 1
  for (int ct = 0; ct < 8; ++ct) {
    const int c0 = js * 1024 + ct * 128;
    const _Float16* brow_h = xhi + (size_t)c0 * DIM;
    const _Float16* brow_l = xlo + (size_t)c0 * DIM;

    f32x4 acc[4][4], accc[4][4];
#pragma unroll
    for (int m = 0; m < 4; ++m)
#pragma unroll
      for (int n = 0; n < 4; ++n) {
        acc[m][n] = (f32x4)0.0f;
        accc[m][n] = (f32x4)0.0f;
      }

#pragma unroll 1
    for (int kt = 0; kt < 16; ++kt) {
      __syncthreads();
#pragma unroll
      for (int h = 0; h < 2; ++h) {
        int go = goff[h] + kt * 32;
        gload_lds16(arow_h + go, smem + 0 + wb[h]);
        gload_lds16(arow_l + go, smem + 8192 + wb[h]);
        gload_lds16(brow_h + go, smem + 16384 + wb[h]);
        gload_lds16(brow_l + go, smem + 24576 + wb[h]);
      }
      __syncthreads();

      f16x8 bhf[4], blf[4];
#pragma unroll
      for (int n = 0; n < 4; ++n) {
        bhf[n] = *(const f16x8*)(smem + 16384 + b_off[n]);
        blf[n] = *(const f16x8*)(smem + 24576 + b_off[n]);
      }
#pragma unroll
      for (int m = 0; m < 4; ++m) {
        f16x8 ahf = *(const f16x8*)(smem + 0 + a_off[m]);
        f16x8 alf = *(const f16x8*)(smem + 8192 + a_off[m]);
#pragma unroll
        for (int n = 0; n < 4; ++n) {
          acc[m][n] = __builtin_amdgcn_mfma_f32_16x16x32_f16(ahf, bhf[n], acc[m][n], 0, 0, 0);
          accc[m][n] = __builtin_amdgcn_mfma_f32_16x16x32_f16(ahf, blf[n], accc[m][n], 0, 0, 0);
          accc[m][n] = __builtin_amdgcn_mfma_f32_16x16x32_f16(alf, bhf[n], accc[m][n], 0, 0, 0);
        }
      }
    }

    // ---- epilogue: d' = sq_j - 2*dot (sq_i dropped: per-row constant) ----
    float sqj[4];
#pragma unroll
    for (int n = 0; n < 4; ++n) sqj[n] = sq[c0 + wn * 64 + n * 16 + (lane & 15)];

#pragma unroll
    for (int p = 0; p < 2; ++p) {
      __syncthreads();
      if (wm == p) {
#pragma unroll
        for (int m = 0; m < 4; ++m)
#pragma unroll
          for (int n = 0; n < 4; ++n) {
            int cl = wn * 64 + n * 16 + (lane & 15);
#pragma unroll
            for (int j = 0; j < 4; ++j) {
              int rl = m * 16 + ((lane >> 4) << 2) + j;
              float dot = acc[m][n][j] + accc[m][n][j] * (1.0f / 2048.0f);
              Df[rl * 132 + cl] = sqj[n] - 2.0f * dot;
            }
          }
      }
      __syncthreads();
#pragma unroll 1
      for (int i = 0; i < 32; ++i) {
        float d = Df[sr * 132 + sc + 4 * i];
        int jg = c0 + sc + 4 * i;
        if (dj_less(d, jg, bd[p][3], bj[p][3])) {
          bd[p][3] = d; bj[p][3] = jg;
#pragma unroll
          for (int q = 3; q > 0; --q) {
            if (dj_less(bd[p][q], bj[p][q], bd[p][q - 1], bj[p][q - 1])) {
              float td = bd[p][q]; bd[p][q] = bd[p][q - 1]; bd[p][q - 1] = td;
              int tj = bj[p][q]; bj[p][q] = bj[p][q - 1]; bj[p][q - 1] = tj;
            }
          }
        }
      }
    }
  }

  // ---- block-level merge: 4 scan-threads per row -> top4 -> cand ----
  __syncthreads();
  float* Pd = (float*)(smem);          // 128*16 f32 = 8 KB (reuse Ah)
  int* Pj = (int*)(smem + 8192);       // 8 KB (reuse Al)
#pragma unroll
  for (int p = 0; p < 2; ++p)
#pragma unroll
    for (int k = 0; k < 4; ++k) {
      Pd[(p * 64 + sr) * 16 + sc * 4 + k] = bd[p][k];
      Pj[(p * 64 + sr) * 16 + sc * 4 + k] = bj[p][k];
    }
  __syncthreads();
  if (tid < 128) {
    float cd[16];
    int cj[16];
#pragma unroll
    for (int s = 0; s < 16; ++s) {
      cd[s] = Pd[tid * 16 + s];
      cj[s] = Pj[tid * 16 + s];
    }
#pragma unroll
    for (int i = 0; i < 16; ++i) {
      int rank = 0;
#pragma unroll
      for (int k = 0; k < 16; ++k) rank += dj_less(cd[k], cj[k], cd[i], cj[i]) ? 1 : 0;
      if (rank < 4) {
        cand_d[(size_t)(row0 + tid) * 32 + js * 4 + rank] = cd[i];
        cand_j[(size_t)(row0 + tid) * 32 + js * 4 + rank] = cj[i];
      }
    }
  }
}

// ---------------- merge 8 j-split candidate lists -> final top4 + index outputs ----------------
__global__ __launch_bounds__(256) void merge_final_kernel(const float* __restrict__ cand_d,
                                                          const int* __restrict__ cand_j,
                                                          int* __restrict__ subsets,
                                                          float* __restrict__ orows,
                                                          float* __restrict__ osubs) {
  int row = blockIdx.x * 256 + threadIdx.x;
  float cd[32];
  int cj[32];
#pragma unroll
  for (int s = 0; s < 32; ++s) {
    cd[s] = cand_d[(size_t)row * 32 + s];
    cj[s] = cand_j[(size_t)row * 32 + s];
  }
#pragma unroll
  for (int i = 0; i < 32; ++i) {
    int rank = 0;
#pragma unroll
    for (int k = 0; k < 32; ++k) rank += dj_less(cd[k], cj[k], cd[i], cj[i]) ? 1 : 0;
    if (rank < 4) {
      subsets[row * 4 + rank] = cj[i];
      orows[row * 4 + rank] = (float)row;
      osubs[row * 4 + rank] = (float)cj[i];
    }
  }
}

// ---------------- gather + mean/max pool -> h0 ----------------
__global__ __launch_bounds__(128) void pool_kernel(const float* __restrict__ x,
                                                   const int* __restrict__ subsets,
                                                   float* __restrict__ h0) {
  int i = blockIdx.x, t = threadIdx.x;
  int s0 = subsets[i * 4 + 0];
  int s1 = subsets[i * 4 + 1];
  int s2 = subsets[i * 4 + 2];
  int s3 = subsets[i * 4 + 3];
  int c = t * 4;
  float4 z0 = *reinterpret_cast<const float4*>(&x[(size_t)s0 * DIM + c]);
  float4 z1 = *reinterpret_cast<const float4*>(&x[(size_t)s1 * DIM + c]);
  float4 z2 = *reinterpret_cast<const float4*>(&x[(size_t)s2 * DIM + c]);
  float4 z3 = *reinterpret_cast<const float4*>(&x[(size_t)s3 * DIM + c]);
  float4 mu, mx;
  mu.x = (z0.x + z1.x + z2.x + z3.x) * 0.25f;
  mu.y = (z0.y + z1.y + z2.y + z3.y) * 0.25f;
  mu.z = (z0.z + z1.z + z2.z + z3.z) * 0.25f;
  mu.w = (z0.w + z1.w + z2.w + z3.w) * 0.25f;
  mx.x = fmaxf(fmaxf(z0.x, z1.x), fmaxf(z2.x, z3.x));
  mx.y = fmaxf(fmaxf(z0.y, z1.y), fmaxf(z2.y, z3.y));
  mx.z = fmaxf(fmaxf(z0.z, z1.z), fmaxf(z2.z, z3.z));
  mx.w = fmaxf(fmaxf(z0.w, z1.w), fmaxf(z2.w, z3.w));
  *reinterpret_cast<float4*>(&h0[(size_t)i * HID + c]) = mu;
  *reinterpret_cast<float4*>(&h0[(size_t)i * HID + DIM + c]) = mx;
}

// ---------------- fp32 GEMM: out = act(A @ W^T + bias) ----------------
__global__ __launch_bounds__(256) void gemm_bias_act_kernel(const float* __restrict__ A,
                                                            const float* __restrict__ W,
                                                            const float* __restrict__ bias,
                                                            float* __restrict__ out,
                                                            int K, int act) {
  __shared__ float As[32][65];
  __shared__ float Bs[32][65];
  const int tid = threadIdx.x;
  const int tx = tid & 15, ty = tid >> 4;
  const int row0 = blockIdx.x * 64, col0 = blockIdx.y * 64;
  float acc[4][4];
#pragma unroll
  for (int m = 0; m < 4; ++m)
#pragma unroll
    for (int n = 0; n < 4; ++n) acc[m][n] = 0.0f;

  for (int kt = 0; kt < K; kt += 32) {
#pragma unroll
    for (int q = 0; q < 2; ++q) {
      int idx = tid * 2 + q;
      int r = idx >> 3;
      int kk = (idx & 7) << 2;
      float4 av = *reinterpret_cast<const float4*>(&A[(size_t)(row0 + r) * K + kt + kk]);
      As[kk + 0][r] = av.x;
      As[kk + 1][r] = av.y;
      As[kk + 2][r] = av.z;
      As[kk + 3][r] = av.w;
      float4 bv = *reinterpret_cast<const float4*>(&W[(size_t)(col0 + r) * K + kt + kk]);
      Bs[kk + 0][r] = bv.x;
      Bs[kk + 1][r] = bv.y;
      Bs[kk + 2][r] = bv.z;
      Bs[kk + 3][r] = bv.w;
    }
    __syncthreads();
#pragma unroll
    for (int k = 0; k < 32; ++k) {
      float a0 = As[k][ty], a1 = As[k][ty + 16], a2 = As[k][ty + 32], a3 = As[k][ty + 48];
      float b0 = Bs[k][tx], b1 = Bs[k][tx + 16], b2 = Bs[k][tx + 32], b3 = Bs[k][tx + 48];
      acc[0][0] = fmaf(a0, b0, acc[0][0]);
      acc[0][1] = fmaf(a0, b1, acc[0][1]);
      acc[0][2] = fmaf(a0, b2, acc[0][2]);
      acc[0][3] = fmaf(a0, b3, acc[0][3]);
      acc[1][0] = fmaf(a1, b0, acc[1][0]);
      acc[1][1] = fmaf(a1, b1, acc[1][1]);
      acc[1][2] = fmaf(a1, b2, acc[1][2]);
      acc[1][3] = fmaf(a1, b3, acc[1][3]);
      acc[2][0] = fmaf(a2, b0, acc[2][0]);
      acc[2][1] = fmaf(a2, b1, acc[2][1]);
      acc[2][2] = fmaf(a2, b2, acc[2][2]);
      acc[2][3] = fmaf(a2, b3, acc[2][3]);
      acc[3][0] = fmaf(a3, b0, acc[3][0]);
      acc[3][1] = fmaf(a3, b1, acc[3][1]);
      acc[3][2] = fmaf(a3, b2, acc[3][2]);
      acc[3][3] = fmaf(a3, b3, acc[3][3]);
    }
    __syncthreads();
  }
#pragma unroll
  for (int m = 0; m < 4; ++m) {
    int rr = row0 + ty + 16 * m;
#pragma unroll
    for (int n = 0; n < 4; ++n) {
      int cc = col0 + tx + 16 * n;
      float v = acc[m][n] + bias[cc];
      if (act && v < 0.0f) v *= 0.01f;
      out[(size_t)rr * HID + cc] = v;
    }
  }
}

// ---------------- final elementwise + entropy partial sums ----------------
__global__ __launch_bounds__(256) void outgen_kernel(const float* __restrict__ x,
                                                     const float* __restrict__ h2,
                                                     const float* __restrict__ eps,
                                                     float* __restrict__ xout,
                                                     float* __restrict__ partials) {
  int tid = threadIdx.x;
  int gid = blockIdx.x * 256 + tid;
  size_t base = (size_t)gid * 4;
  int i = (int)(base >> 9);
  int c = (int)(base & 511);
  float4 xv = *reinterpret_cast<const float4*>(&x[base]);
  float4 ev = *reinterpret_cast<const float4*>(&eps[base]);
  float4 mu = *reinterpret_cast<const float4*>(&h2[(size_t)i * HID + c]);
  float4 hs = *reinterpret_cast<const float4*>(&h2[(size_t)i * HID + DIM + c]);
  float4 xo;
  xo.x = xv.x + mu.x + expf(0.5f * hs.x) * ev.x;
  xo.y = xv.y + mu.y + expf(0.5f * hs.y) * ev.y;
  xo.z = xv.z + mu.z + expf(0.5f * hs.z) * ev.z;
  xo.w = xv.w + mu.w + expf(0.5f * hs.w) * ev.w;
  *reinterpret_cast<float4*>(&xout[base]) = xo;
  float lsum = hs.x + hs.y + hs.z + hs.w;
  for (int off = 32; off > 0; off >>= 1) lsum += __shfl_down(lsum, off);
  __shared__ float red[4];
  if ((tid & 63) == 0) red[tid >> 6] = lsum;
  __syncthreads();
  if (tid == 0) partials[blockIdx.x] = red[0] + red[1] + red[2] + red[3];
}

__global__ __launch_bounds__(256) void entfin_kernel(const float* __restrict__ partials,
                                                     float* __restrict__ ent) {
  int t = threadIdx.x;
  float s = 0.0f;
  for (int q = 0; q < 16; ++q) s += partials[t + 256 * q];
  for (int off = 32; off > 0; off >>= 1) s += __shfl_down(s, off);
  __shared__ float red[4];
  if ((t & 63) == 0) red[t >> 6] = s;
  __syncthreads();
  if (t == 0)
    ent[0] = 0.5f + 0.9189385332046727f +
             0.5f * (red[0] + red[1] + red[2] + red[3]) / (8192.0f * 512.0f);
}

extern "C" void kernel_launch(void* const* d_in, const int* in_sizes, int n_in,
                              void* d_out, int out_size, void* d_ws, size_t ws_size,
                              hipStream_t stream) {
  const float* x = (const float*)d_in[0];
  const float* W1 = (const float*)d_in[1];
  const float* b1 = (const float*)d_in[2];
  const float* W2 = (const float*)d_in[3];
  const float* b2 = (const float*)d_in[4];
  const float* eps = (const float*)d_in[5];

  float* out = (float*)d_out;
  float* ws = (float*)d_ws;

  // workspace layout (float offsets)
  float* sq = ws;                               // 8192
  int* subsets = (int*)(ws + 8192);             // 32768 ints
  float* cand_d = ws + 40960;                   // 8192*32
  int* cand_j = (int*)(ws + 303104);            // 8192*32 ints
  float* partials = ws + 565248;                // 4096
  float* h0 = ws + 1048576;                     // 8192*1024
  float* h1 = ws + 9437184;                     // 8192*1024
  float* h2 = h0;                               // reuse after gemm1
  // xhi/xlo overlap h1's region (dead until gemm1)
  _Float16* xhi = (_Float16*)(ws + 9437184);    // 8192*512 halves
  _Float16* xlo = (_Float16*)(ws + 11534336);   // 8192*512 halves

  float* xout = out;
  float* ent = out + (size_t)N_ROWS * DIM;
  float* orows = ent + 1;
  float* osubs = orows + (size_t)N_ROWS * 4;

  rowsq_kernel<<<N_ROWS, 64, 0, stream>>>(x, sq);
  split_kernel<<<4096, 256, 0, stream>>>(x, xhi, xlo);
  dist_top4_mfma<<<dim3(64, 8), 256, 0, stream>>>(xhi, xlo, sq, cand_d, cand_j);
  merge_final_kernel<<<32, 256, 0, stream>>>(cand_d, cand_j, subsets, orows, osubs);
  pool_kernel<<<N_ROWS, 128, 0, stream>>>(x, subsets, h0);
  gemm_bias_act_kernel<<<dim3(128, 16), 256, 0, stream>>>(h0, W1, b1, h1, HID, 1);
  gemm_bias_act_kernel<<<dim3(128, 16), 256, 0, stream>>>(h1, W2, b2, h2, HID, 0);
  outgen_kernel<<<4096, 256, 0, stream>>>(x, h2, eps, xout, partials);
  entfin_kernel<<<1, 256, 0, stream>>>(partials, ent);
}

// Round 3
// 381.807 us; speedup vs baseline: 5.5079x; 2.4673x over previous
//
#include <hip/hip_runtime.h>
#include <math.h>

#define N_ROWS 8192
#define DIM 512
#define HID 1024

typedef _Float16 f16x8 __attribute__((ext_vector_type(8)));
typedef _Float16 f16x4 __attribute__((ext_vector_type(4)));
typedef float f32x4 __attribute__((ext_vector_type(4)));

__device__ __forceinline__ bool dj_less(float d1, int j1, float d2, int j2) {
  return (d1 < d2) || (d1 == d2 && j1 < j2);
}

__device__ __forceinline__ void gload_lds16(const void* g, void* s) {
  __builtin_amdgcn_global_load_lds((const __attribute__((address_space(1))) void*)g,
                                   (__attribute__((address_space(3))) void*)s, 16, 0, 0);
}

#define S_SWZ(r) ((((r) & 3) ^ (((r) >> 2) & 3)))

// ---------------- split fp32 -> f16 hi + scaled lo, fused row sq-norms ----------------
__global__ __launch_bounds__(256) void split_rowsq_kernel(const float* __restrict__ x,
                                                          _Float16* __restrict__ xhi,
                                                          _Float16* __restrict__ xlo,
                                                          float* __restrict__ sq) {
  int tid = threadIdx.x;
  int g = blockIdx.x * 256 + tid;
  float4 v = reinterpret_cast<const float4*>(x)[g];
  _Float16 h0 = (_Float16)v.x, h1 = (_Float16)v.y, h2 = (_Float16)v.z, h3 = (_Float16)v.w;
  _Float16 l0 = (_Float16)((v.x - (float)h0) * 2048.0f);
  _Float16 l1 = (_Float16)((v.y - (float)h1) * 2048.0f);
  _Float16 l2 = (_Float16)((v.z - (float)h2) * 2048.0f);
  _Float16 l3 = (_Float16)((v.w - (float)h3) * 2048.0f);
  f16x4 hv = {h0, h1, h2, h3};
  f16x4 lv = {l0, l1, l2, l3};
  reinterpret_cast<f16x4*>(xhi)[g] = hv;
  reinterpret_cast<f16x4*>(xlo)[g] = lv;
  // row sum-of-squares: 128 consecutive threads = one row (2 rows per block)
  float s = v.x * v.x + v.y * v.y + v.z * v.z + v.w * v.w;
  for (int off = 32; off > 0; off >>= 1) s += __shfl_down(s, off);
  __shared__ float red[4];
  if ((tid & 63) == 0) red[tid >> 6] = s;
  __syncthreads();
  if (tid == 0) sq[blockIdx.x * 2] = red[0] + red[1];
  if (tid == 128) sq[blockIdx.x * 2 + 1] = red[2] + red[3];
}

// ---------------- f32 -> f16 (weights) ----------------
__global__ __launch_bounds__(256) void f32tof16_kernel(const float* __restrict__ in,
                                                       _Float16* __restrict__ out) {
  int g = blockIdx.x * 256 + threadIdx.x;
  float4 v = reinterpret_cast<const float4*>(in)[g];
  f16x4 h = {(_Float16)v.x, (_Float16)v.y, (_Float16)v.z, (_Float16)v.w};
  reinterpret_cast<f16x4*>(out)[g] = h;
}

// ---------------- MFMA distance + per-row top4 (partial over 8 j-splits) ----------------
// grid (64 row-tiles, 8 j-splits), block 256 (4 waves, 2x2).  Tile 128x128, BK=32.
__global__ __launch_bounds__(256, 2) void dist_top4_mfma(const _Float16* __restrict__ xhi,
                                                         const _Float16* __restrict__ xlo,
                                                         const float* __restrict__ sq,
                                                         float* __restrict__ cand_d,
                                                         int* __restrict__ cand_j) {
  // LDS: Ah[0,8K) Al[8K,16K) Bh[16K,24K) Bl[24K,32K) bytes ; D f32[64][132] at 32768
  __shared__ char smem[66560];
  float* Df = (float*)(smem + 32768);
  const int tid = threadIdx.x;
  const int lane = tid & 63;
  const int w = tid >> 6;
  const int wm = w >> 1, wn = w & 1;
  const int row0 = blockIdx.x * 128;
  const int js = blockIdx.y;

  int a_off[4], b_off[4];
#pragma unroll
  for (int m = 0; m < 4; ++m) {
    int r = wm * 64 + m * 16 + (lane & 15);
    a_off[m] = r * 64 + (((lane >> 4) ^ S_SWZ(r)) * 16);
  }
#pragma unroll
  for (int n = 0; n < 4; ++n) {
    int r = wn * 64 + n * 16 + (lane & 15);
    b_off[n] = r * 64 + (((lane >> 4) ^ S_SWZ(r)) * 16);
  }

  int goff[2], wb[2];
#pragma unroll
  for (int h = 0; h < 2; ++h) {
    int i = h * 256 + tid;
    int r = i >> 2, cs = i & 3;
    int c = cs ^ S_SWZ(r);
    goff[h] = r * 512 + c * 8;        // f16 elements
    wb[h] = h * 4096 + w * 1024;      // bytes, wave-uniform
  }

  const int sr = tid >> 2;
  const int sc = tid & 3;

  float bd[2][4];
  int bj[2][4];
#pragma unroll
  for (int p = 0; p < 2; ++p)
#pragma unroll
    for (int k = 0; k < 4; ++k) { bd[p][k] = 3.0e38f; bj[p][k] = 0x7fffffff; }

  const _Float16* arow_h = xhi + (size_t)row0 * DIM;
  const _Float16* arow_l = xlo + (size_t)row0 * DIM;

#pragma unroll 1
  for (int ct = 0; ct < 8; ++ct) {
    const int c0 = js * 1024 + ct * 128;
    const _Float16* brow_h = xhi + (size_t)c0 * DIM;
    const _Float16* brow_l = xlo + (size_t)c0 * DIM;

    f32x4 acc[4][4], accc[4][4];
#pragma unroll
    for (int m = 0; m < 4; ++m)
#pragma unroll
      for (int n = 0; n < 4; ++n) {
        acc[m][n] = (f32x4)0.0f;
        accc[m][n] = (f32x4)0.0f;
      }

#pragma unroll 1
    for (int kt = 0; kt < 16; ++kt) {
      __syncthreads();
#pragma unroll
      for (int h = 0; h < 2; ++h) {
        int go = goff[h] + kt * 32;
        gload_lds16(arow_h + go, smem + 0 + wb[h]);
        gload_lds16(arow_l + go, smem + 8192 + wb[h]);
        gload_lds16(brow_h + go, smem + 16384 + wb[h]);
        gload_lds16(brow_l + go, smem + 24576 + wb[h]);
      }
      __syncthreads();

      f16x8 bhf[4], blf[4];
#pragma unroll
      for (int n = 0; n < 4; ++n) {
        bhf[n] = *(const f16x8*)(smem + 16384 + b_off[n]);
        blf[n] = *(const f16x8*)(smem + 24576 + b_off[n]);
      }
#pragma unroll
      for (int m = 0; m < 4; ++m) {
        f16x8 ahf = *(const f16x8*)(smem + 0 + a_off[m]);
        f16x8 alf = *(const f16x8*)(smem + 8192 + a_off[m]);
#pragma unroll
        for (int n = 0; n < 4; ++n) {
          acc[m][n] = __builtin_amdgcn_mfma_f32_16x16x32_f16(ahf, bhf[n], acc[m][n], 0, 0, 0);
          accc[m][n] = __builtin_amdgcn_mfma_f32_16x16x32_f16(ahf, blf[n], accc[m][n], 0, 0, 0);
          accc[m][n] = __builtin_amdgcn_mfma_f32_16x16x32_f16(alf, bhf[n], accc[m][n], 0, 0, 0);
        }
      }
    }

    float sqj[4];
#pragma unroll
    for (int n = 0; n < 4; ++n) sqj[n] = sq[c0 + wn * 64 + n * 16 + (lane & 15)];

#pragma unroll
    for (int p = 0; p < 2; ++p) {
      __syncthreads();
      if (wm == p) {
#pragma unroll
        for (int m = 0; m < 4; ++m)
#pragma unroll
          for (int n = 0; n < 4; ++n) {
            int cl = wn * 64 + n * 16 + (lane & 15);
#pragma unroll
            for (int j = 0; j < 4; ++j) {
              int rl = m * 16 + ((lane >> 4) << 2) + j;
              float dot = acc[m][n][j] + accc[m][n][j] * (1.0f / 2048.0f);
              Df[rl * 132 + cl] = sqj[n] - 2.0f * dot;
            }
          }
      }
      __syncthreads();
#pragma unroll 1
      for (int i = 0; i < 32; ++i) {
        float d = Df[sr * 132 + sc + 4 * i];
        int jg = c0 + sc + 4 * i;
        if (dj_less(d, jg, bd[p][3], bj[p][3])) {
          bd[p][3] = d; bj[p][3] = jg;
#pragma unroll
          for (int q = 3; q > 0; --q) {
            if (dj_less(bd[p][q], bj[p][q], bd[p][q - 1], bj[p][q - 1])) {
              float td = bd[p][q]; bd[p][q] = bd[p][q - 1]; bd[p][q - 1] = td;
              int tj = bj[p][q]; bj[p][q] = bj[p][q - 1]; bj[p][q - 1] = tj;
            }
          }
        }
      }
    }
  }

  __syncthreads();
  float* Pd = (float*)(smem);
  int* Pj = (int*)(smem + 8192);
#pragma unroll
  for (int p = 0; p < 2; ++p)
#pragma unroll
    for (int k = 0; k < 4; ++k) {
      Pd[(p * 64 + sr) * 16 + sc * 4 + k] = bd[p][k];
      Pj[(p * 64 + sr) * 16 + sc * 4 + k] = bj[p][k];
    }
  __syncthreads();
  if (tid < 128) {
    float cd[16];
    int cj[16];
#pragma unroll
    for (int s = 0; s < 16; ++s) {
      cd[s] = Pd[tid * 16 + s];
      cj[s] = Pj[tid * 16 + s];
    }
#pragma unroll
    for (int i = 0; i < 16; ++i) {
      int rank = 0;
#pragma unroll
      for (int k = 0; k < 16; ++k) rank += dj_less(cd[k], cj[k], cd[i], cj[i]) ? 1 : 0;
      if (rank < 4) {
        cand_d[(size_t)(row0 + tid) * 32 + js * 4 + rank] = cd[i];
        cand_j[(size_t)(row0 + tid) * 32 + js * 4 + rank] = cj[i];
      }
    }
  }
}

// ---------------- merge 8 j-split candidate lists -> final top4 + index outputs ----------------
__global__ __launch_bounds__(256) void merge_final_kernel(const float* __restrict__ cand_d,
                                                          const int* __restrict__ cand_j,
                                                          int* __restrict__ subsets,
                                                          float* __restrict__ orows,
                                                          float* __restrict__ osubs) {
  int row = blockIdx.x * 256 + threadIdx.x;
  float cd[32];
  int cj[32];
#pragma unroll
  for (int s = 0; s < 32; ++s) {
    cd[s] = cand_d[(size_t)row * 32 + s];
    cj[s] = cand_j[(size_t)row * 32 + s];
  }
#pragma unroll
  for (int i = 0; i < 32; ++i) {
    int rank = 0;
#pragma unroll
    for (int k = 0; k < 32; ++k) rank += dj_less(cd[k], cj[k], cd[i], cj[i]) ? 1 : 0;
    if (rank < 4) {
      subsets[row * 4 + rank] = cj[i];
      orows[row * 4 + rank] = (float)row;
      osubs[row * 4 + rank] = (float)cj[i];
    }
  }
}

// ---------------- gather + mean/max pool -> h0 (f16) ----------------
__global__ __launch_bounds__(128) void pool_kernel(const float* __restrict__ x,
                                                   const int* __restrict__ subsets,
                                                   _Float16* __restrict__ h0) {
  int i = blockIdx.x, t = threadIdx.x;
  int s0 = subsets[i * 4 + 0];
  int s1 = subsets[i * 4 + 1];
  int s2 = subsets[i * 4 + 2];
  int s3 = subsets[i * 4 + 3];
  int c = t * 4;
  float4 z0 = *reinterpret_cast<const float4*>(&x[(size_t)s0 * DIM + c]);
  float4 z1 = *reinterpret_cast<const float4*>(&x[(size_t)s1 * DIM + c]);
  float4 z2 = *reinterpret_cast<const float4*>(&x[(size_t)s2 * DIM + c]);
  float4 z3 = *reinterpret_cast<const float4*>(&x[(size_t)s3 * DIM + c]);
  f16x4 mu, mx;
  mu[0] = (_Float16)((z0.x + z1.x + z2.x + z3.x) * 0.25f);
  mu[1] = (_Float16)((z0.y + z1.y + z2.y + z3.y) * 0.25f);
  mu[2] = (_Float16)((z0.z + z1.z + z2.z + z3.z) * 0.25f);
  mu[3] = (_Float16)((z0.w + z1.w + z2.w + z3.w) * 0.25f);
  mx[0] = (_Float16)fmaxf(fmaxf(z0.x, z1.x), fmaxf(z2.x, z3.x));
  mx[1] = (_Float16)fmaxf(fmaxf(z0.y, z1.y), fmaxf(z2.y, z3.y));
  mx[2] = (_Float16)fmaxf(fmaxf(z0.z, z1.z), fmaxf(z2.z, z3.z));
  mx[3] = (_Float16)fmaxf(fmaxf(z0.w, z1.w), fmaxf(z2.w, z3.w));
  *reinterpret_cast<f16x4*>(&h0[(size_t)i * HID + c]) = mu;
  *reinterpret_cast<f16x4*>(&h0[(size_t)i * HID + DIM + c]) = mx;
}

// ---------------- f16 MFMA GEMM: out = act(A @ W^T + bias) ----------------
// A (8192 x 1024 f16), W (1024 x 1024 f16).  Tile 128x128, BK=32, grid (64,8).
// act=1: leaky-relu, store f16 to out16.  act=0: store f32 to out32.
__global__ __launch_bounds__(256, 2) void gemm_mfma_kernel(const _Float16* __restrict__ A,
                                                           const _Float16* __restrict__ W,
                                                           const float* __restrict__ bias,
                                                           _Float16* __restrict__ out16,
                                                           float* __restrict__ out32,
                                                           int act) {
  __shared__ char smem[16384];  // A-tile 8K, B-tile 8K
  const int tid = threadIdx.x;
  const int lane = tid & 63;
  const int w = tid >> 6;
  const int wm = w >> 1, wn = w & 1;
  const int row0 = blockIdx.x * 128;
  const int col0 = blockIdx.y * 128;

  int a_off[4], b_off[4];
#pragma unroll
  for (int m = 0; m < 4; ++m) {
    int r = wm * 64 + m * 16 + (lane & 15);
    a_off[m] = r * 64 + (((lane >> 4) ^ S_SWZ(r)) * 16);
  }
#pragma unroll
  for (int n = 0; n < 4; ++n) {
    int r = wn * 64 + n * 16 + (lane & 15);
    b_off[n] = r * 64 + (((lane >> 4) ^ S_SWZ(r)) * 16);
  }

  int goff[2], wb[2];
#pragma unroll
  for (int h = 0; h < 2; ++h) {
    int i = h * 256 + tid;
    int r = i >> 2, cs = i & 3;
    int c = cs ^ S_SWZ(r);
    goff[h] = r * HID + c * 8;        // f16 elements (row stride K=1024)
    wb[h] = h * 4096 + w * 1024;      // bytes, wave-uniform
  }

  const _Float16* arow = A + (size_t)row0 * HID;
  const _Float16* brow = W + (size_t)col0 * HID;

  f32x4 acc[4][4];
#pragma unroll
  for (int m = 0; m < 4; ++m)
#pragma unroll
    for (int n = 0; n < 4; ++n) acc[m][n] = (f32x4)0.0f;

#pragma unroll 1
  for (int kt = 0; kt < 32; ++kt) {
    __syncthreads();
#pragma unroll
    for (int h = 0; h < 2; ++h) {
      int go = goff[h] + kt * 32;
      gload_lds16(arow + go, smem + 0 + wb[h]);
      gload_lds16(brow + go, smem + 8192 + wb[h]);
    }
    __syncthreads();

    f16x8 bf[4];
#pragma unroll
    for (int n = 0; n < 4; ++n) bf[n] = *(const f16x8*)(smem + 8192 + b_off[n]);
#pragma unroll
    for (int m = 0; m < 4; ++m) {
      f16x8 af = *(const f16x8*)(smem + 0 + a_off[m]);
#pragma unroll
      for (int n = 0; n < 4; ++n)
        acc[m][n] = __builtin_amdgcn_mfma_f32_16x16x32_f16(af, bf[n], acc[m][n], 0, 0, 0);
    }
  }

  float bv[4];
#pragma unroll
  for (int n = 0; n < 4; ++n) bv[n] = bias[col0 + wn * 64 + n * 16 + (lane & 15)];

#pragma unroll
  for (int m = 0; m < 4; ++m)
#pragma unroll
    for (int n = 0; n < 4; ++n) {
      int cl = col0 + wn * 64 + n * 16 + (lane & 15);
#pragma unroll
      for (int j = 0; j < 4; ++j) {
        int rl = row0 + wm * 64 + m * 16 + ((lane >> 4) << 2) + j;
        float v = acc[m][n][j] + bv[n];
        if (act) {
          if (v < 0.0f) v *= 0.01f;
          out16[(size_t)rl * HID + cl] = (_Float16)v;
        } else {
          out32[(size_t)rl * HID + cl] = v;
        }
      }
    }
}

// ---------------- final elementwise + entropy partial sums ----------------
__global__ __launch_bounds__(256) void outgen_kernel(const float* __restrict__ x,
                                                     const float* __restrict__ h2,
                                                     const float* __restrict__ eps,
                                                     float* __restrict__ xout,
                                                     float* __restrict__ partials) {
  int tid = threadIdx.x;
  int gid = blockIdx.x * 256 + tid;
  size_t base = (size_t)gid * 4;
  int i = (int)(base >> 9);
  int c = (int)(base & 511);
  float4 xv = *reinterpret_cast<const float4*>(&x[base]);
  float4 ev = *reinterpret_cast<const float4*>(&eps[base]);
  float4 mu = *reinterpret_cast<const float4*>(&h2[(size_t)i * HID + c]);
  float4 hs = *reinterpret_cast<const float4*>(&h2[(size_t)i * HID + DIM + c]);
  float4 xo;
  xo.x = xv.x + mu.x + expf(0.5f * hs.x) * ev.x;
  xo.y = xv.y + mu.y + expf(0.5f * hs.y) * ev.y;
  xo.z = xv.z + mu.z + expf(0.5f * hs.z) * ev.z;
  xo.w = xv.w + mu.w + expf(0.5f * hs.w) * ev.w;
  *reinterpret_cast<float4*>(&xout[base]) = xo;
  float lsum = hs.x + hs.y + hs.z + hs.w;
  for (int off = 32; off > 0; off >>= 1) lsum += __shfl_down(lsum, off);
  __shared__ float red[4];
  if ((tid & 63) == 0) red[tid >> 6] = lsum;
  __syncthreads();
  if (tid == 0) partials[blockIdx.x] = red[0] + red[1] + red[2] + red[3];
}

__global__ __launch_bounds__(256) void entfin_kernel(const float* __restrict__ partials,
                                                     float* __restrict__ ent) {
  int t = threadIdx.x;
  float s = 0.0f;
  for (int q = 0; q < 16; ++q) s += partials[t + 256 * q];
  for (int off = 32; off > 0; off >>= 1) s += __shfl_down(s, off);
  __shared__ float red[4];
  if ((t & 63) == 0) red[t >> 6] = s;
  __syncthreads();
  if (t == 0)
    ent[0] = 0.5f + 0.9189385332046727f +
             0.5f * (red[0] + red[1] + red[2] + red[3]) / (8192.0f * 512.0f);
}

extern "C" void kernel_launch(void* const* d_in, const int* in_sizes, int n_in,
                              void* d_out, int out_size, void* d_ws, size_t ws_size,
                              hipStream_t stream) {
  const float* x = (const float*)d_in[0];
  const float* W1 = (const float*)d_in[1];
  const float* b1 = (const float*)d_in[2];
  const float* W2 = (const float*)d_in[3];
  const float* b2 = (const float*)d_in[4];
  const float* eps = (const float*)d_in[5];

  float* out = (float*)d_out;
  float* ws = (float*)d_ws;

  // workspace layout (float offsets)
  float* sq = ws;                               // 8192
  int* subsets = (int*)(ws + 8192);             // 32768 ints
  float* cand_d = ws + 40960;                   // 8192*32
  int* cand_j = (int*)(ws + 303104);            // 8192*32 ints
  float* partials = ws + 565248;                // 4096
  float* h2 = ws + 1048576;                     // 8192*1024 f32
  _Float16* xhi = (_Float16*)(ws + 9437184);    // 8192*512 halves (dead after dist)
  _Float16* xlo = (_Float16*)(ws + 11534336);   // 8192*512 halves (dead after dist)
  _Float16* h0f = (_Float16*)(ws + 9437184);    // 8192*1024 halves, overlaps xhi/xlo
  _Float16* h1f = (_Float16*)(ws + 13631488);   // 8192*1024 halves
  _Float16* W1f = (_Float16*)(ws + 17825792);   // 1024*1024 halves
  _Float16* W2f = (_Float16*)(ws + 18350080);   // 1024*1024 halves

  float* xout = out;
  float* ent = out + (size_t)N_ROWS * DIM;
  float* orows = ent + 1;
  float* osubs = orows + (size_t)N_ROWS * 4;

  split_rowsq_kernel<<<4096, 256, 0, stream>>>(x, xhi, xlo, sq);
  f32tof16_kernel<<<1024, 256, 0, stream>>>(W1, W1f);
  f32tof16_kernel<<<1024, 256, 0, stream>>>(W2, W2f);
  dist_top4_mfma<<<dim3(64, 8), 256, 0, stream>>>(xhi, xlo, sq, cand_d, cand_j);
  merge_final_kernel<<<32, 256, 0, stream>>>(cand_d, cand_j, subsets, orows, osubs);
  pool_kernel<<<N_ROWS, 128, 0, stream>>>(x, subsets, h0f);
  gemm_mfma_kernel<<<dim3(64, 8), 256, 0, stream>>>(h0f, W1f, b1, h1f, (float*)0, 1);
  gemm_mfma_kernel<<<dim3(64, 8), 256, 0, stream>>>(h1f, W2f, b2, (_Float16*)0, h2, 0);
  outgen_kernel<<<4096, 256, 0, stream>>>(x, h2, eps, xout, partials);
  entfin_kernel<<<1, 256, 0, stream>>>(partials, ent);
}

// Round 4
// 296.253 us; speedup vs baseline: 7.0985x; 1.2888x over previous
//
#include <hip/hip_runtime.h>
#include <math.h>

#define N_ROWS 8192
#define DIM 512
#define HID 1024

typedef _Float16 f16x8 __attribute__((ext_vector_type(8)));
typedef _Float16 f16x4 __attribute__((ext_vector_type(4)));
typedef float f32x4 __attribute__((ext_vector_type(4)));

__device__ __forceinline__ bool dj_less(float d1, int j1, float d2, int j2) {
  return (d1 < d2) || (d1 == d2 && j1 < j2);
}

__device__ __forceinline__ void gload_lds16(const void* g, void* s) {
  __builtin_amdgcn_global_load_lds((const __attribute__((address_space(1))) void*)g,
                                   (__attribute__((address_space(3))) void*)s, 16, 0, 0);
}

#define S_SWZ(r) ((((r) & 3) ^ (((r) >> 2) & 3)))

// ---------------- fp32 -> f16 + fused row sq-norms ----------------
__global__ __launch_bounds__(256) void tof16_rowsq_kernel(const float* __restrict__ x,
                                                          _Float16* __restrict__ xh,
                                                          float* __restrict__ sq) {
  int tid = threadIdx.x;
  int g = blockIdx.x * 256 + tid;
  float4 v = reinterpret_cast<const float4*>(x)[g];
  f16x4 hv = {(_Float16)v.x, (_Float16)v.y, (_Float16)v.z, (_Float16)v.w};
  reinterpret_cast<f16x4*>(xh)[g] = hv;
  // 128 consecutive threads = one row (2 rows per block)
  float s = v.x * v.x + v.y * v.y + v.z * v.z + v.w * v.w;
  for (int off = 32; off > 0; off >>= 1) s += __shfl_down(s, off);
  __shared__ float red[4];
  if ((tid & 63) == 0) red[tid >> 6] = s;
  __syncthreads();
  if (tid == 0) sq[blockIdx.x * 2] = red[0] + red[1];
  if (tid == 128) sq[blockIdx.x * 2 + 1] = red[2] + red[3];
}

// ---------------- f32 -> f16 (weights) ----------------
__global__ __launch_bounds__(256) void f32tof16_kernel(const float* __restrict__ in,
                                                       _Float16* __restrict__ out) {
  int g = blockIdx.x * 256 + threadIdx.x;
  float4 v = reinterpret_cast<const float4*>(in)[g];
  f16x4 h = {(_Float16)v.x, (_Float16)v.y, (_Float16)v.z, (_Float16)v.w};
  reinterpret_cast<f16x4*>(out)[g] = h;
}

// ---------------- 1-pass f16 MFMA distance + per-row top8 keys (8 j-splits) ----------------
// grid (64, 8), block 256 (4 waves 2x2). Tile 128x128, BK=32.
// key = monotone_u32(trunc(d~ - 256)) | j  (low 13 bits = global col index)
__global__ __launch_bounds__(256, 4) void dist_top8_mfma(const _Float16* __restrict__ xh,
                                                         const float* __restrict__ sq,
                                                         unsigned int* __restrict__ cand) {
  // LDS: A[0,8K) B[8K,16K) ; Dk u32[64][132] at 16384 ; merge Pk u32[128][33] at 0
  __shared__ __align__(16) char smem[50688];
  unsigned int* Dk = (unsigned int*)(smem + 16384);
  const int tid = threadIdx.x;
  const int lane = tid & 63;
  const int w = tid >> 6;
  const int wm = w >> 1, wn = w & 1;
  const int row0 = blockIdx.x * 128;
  const int js = blockIdx.y;

  int a_off[4], b_off[4];
#pragma unroll
  for (int m = 0; m < 4; ++m) {
    int r = wm * 64 + m * 16 + (lane & 15);
    a_off[m] = r * 64 + (((lane >> 4) ^ S_SWZ(r)) * 16);
  }
#pragma unroll
  for (int n = 0; n < 4; ++n) {
    int r = wn * 64 + n * 16 + (lane & 15);
    b_off[n] = r * 64 + (((lane >> 4) ^ S_SWZ(r)) * 16);
  }

  int goff[2], wb[2];
#pragma unroll
  for (int h = 0; h < 2; ++h) {
    int i = h * 256 + tid;
    int r = i >> 2, cs = i & 3;
    int c = cs ^ S_SWZ(r);
    goff[h] = r * 512 + c * 8;        // f16 elements
    wb[h] = h * 4096 + w * 1024;      // bytes, wave-uniform
  }

  const int sr = tid >> 2;   // scan row 0..63
  const int sc = tid & 3;    // scan col phase 0..3

  unsigned int keys[2][8];
#pragma unroll
  for (int p = 0; p < 2; ++p)
#pragma unroll
    for (int q = 0; q < 8; ++q) keys[p][q] = 0xFFFFFFFFu;

  const _Float16* arow = xh + (size_t)row0 * DIM;

#pragma unroll 1
  for (int ct = 0; ct < 8; ++ct) {
    const int c0 = js * 1024 + ct * 128;
    const _Float16* brow = xh + (size_t)c0 * DIM;

    f32x4 acc[4][4];
#pragma unroll
    for (int m = 0; m < 4; ++m)
#pragma unroll
      for (int n = 0; n < 4; ++n) acc[m][n] = (f32x4)0.0f;

#pragma unroll 1
    for (int kt = 0; kt < 16; ++kt) {
      __syncthreads();
#pragma unroll
      for (int h = 0; h < 2; ++h) {
        int go = goff[h] + kt * 32;
        gload_lds16(arow + go, smem + 0 + wb[h]);
        gload_lds16(brow + go, smem + 8192 + wb[h]);
      }
      __syncthreads();

      f16x8 bf[4];
#pragma unroll
      for (int n = 0; n < 4; ++n) bf[n] = *(const f16x8*)(smem + 8192 + b_off[n]);
#pragma unroll
      for (int m = 0; m < 4; ++m) {
        f16x8 af = *(const f16x8*)(smem + 0 + a_off[m]);
#pragma unroll
        for (int n = 0; n < 4; ++n)
          acc[m][n] = __builtin_amdgcn_mfma_f32_16x16x32_f16(af, bf[n], acc[m][n], 0, 0, 0);
      }
    }

    float sqj[4];
#pragma unroll
    for (int n = 0; n < 4; ++n) sqj[n] = sq[c0 + wn * 64 + n * 16 + (lane & 15)];

#pragma unroll
    for (int p = 0; p < 2; ++p) {
      __syncthreads();
      if (wm == p) {
#pragma unroll
        for (int m = 0; m < 4; ++m)
#pragma unroll
          for (int n = 0; n < 4; ++n) {
            int cl = wn * 64 + n * 16 + (lane & 15);
#pragma unroll
            for (int j = 0; j < 4; ++j) {
              int rl = m * 16 + ((lane >> 4) << 2) + j;
              float v = (sqj[n] - 2.0f * acc[m][n][j]) - 256.0f;
              unsigned int u = __float_as_uint(v);
              unsigned int kk = (v >= 0.0f) ? (u | 0x80000000u) : ~u;
              Dk[rl * 132 + cl] = (kk & 0xFFFFE000u) | (unsigned int)(c0 + cl);
            }
          }
      }
      __syncthreads();
#pragma unroll 4
      for (int i = 0; i < 32; ++i) {
        unsigned int k = Dk[sr * 132 + sc + 4 * i];
        if (k < keys[p][7]) {
          keys[p][7] = k;
#pragma unroll
          for (int q = 7; q > 0; --q) {
            if (keys[p][q] < keys[p][q - 1]) {
              unsigned int t = keys[p][q];
              keys[p][q] = keys[p][q - 1];
              keys[p][q - 1] = t;
            }
          }
        }
      }
    }
  }

  // ---- block merge: per row, 4 threads x 8 keys -> split top-8 ----
  __syncthreads();
  unsigned int* Pk = (unsigned int*)smem;  // [128][33]
#pragma unroll
  for (int p = 0; p < 2; ++p)
#pragma unroll
    for (int q = 0; q < 8; ++q) Pk[(p * 64 + sr) * 33 + sc * 8 + q] = keys[p][q];
  __syncthreads();
  {
    int r = tid >> 1, half = tid & 1;
    unsigned int kk[32];
#pragma unroll
    for (int e = 0; e < 32; ++e) kk[e] = Pk[r * 33 + e];
#pragma unroll
    for (int i = 0; i < 16; ++i) {
      unsigned int ki = kk[half * 16 + i];
      int rank = 0;
#pragma unroll
      for (int e = 0; e < 32; ++e) rank += (kk[e] < ki) ? 1 : 0;
      if (rank < 8) cand[(size_t)(row0 + r) * 64 + js * 8 + rank] = ki;
    }
  }
}

// ---------------- rescore: merge 64 cands, exact fp32 top-4 ----------------
// one wave per row
__global__ __launch_bounds__(64) void rescore_kernel(const float* __restrict__ x,
                                                     const float* __restrict__ sq,
                                                     const unsigned int* __restrict__ cand,
                                                     int* __restrict__ subsets,
                                                     float* __restrict__ orows,
                                                     float* __restrict__ osubs) {
  const int row = blockIdx.x;
  const int lane = threadIdx.x;
  unsigned int key = cand[(size_t)row * 64 + lane];
  int rank = 0;
#pragma unroll 8
  for (int k = 0; k < 64; ++k) {
    unsigned int kk = __shfl(key, k);
    rank += (kk < key) ? 1 : 0;
  }
  __shared__ unsigned int c16[16];
  if (rank < 16) c16[rank] = key & 0x1FFFu;
  __syncthreads();

  const float4* xi = reinterpret_cast<const float4*>(x + (size_t)row * DIM);
  float4 xa = xi[lane];
  float4 xb = xi[lane + 64];
  float sqi = sq[row];

  float dme = 0.0f;
  int jme = 0;
#pragma unroll 1
  for (int c = 0; c < 16; ++c) {
    int j = (int)c16[c];
    const float4* xj = reinterpret_cast<const float4*>(x + (size_t)j * DIM);
    float4 ya = xj[lane];
    float4 yb = xj[lane + 64];
    float dot = xa.x * ya.x + xa.y * ya.y + xa.z * ya.z + xa.w * ya.w +
                xb.x * yb.x + xb.y * yb.y + xb.z * yb.z + xb.w * yb.w;
#pragma unroll
    for (int off = 32; off > 0; off >>= 1) dot += __shfl_xor(dot, off);
    float d = sqi + sq[j] - 2.0f * dot;
    if (lane == c) { dme = d; jme = j; }
  }

  int rank2 = 0;
#pragma unroll
  for (int k = 0; k < 16; ++k) {
    float dk = __shfl(dme, k);
    int jk = __shfl(jme, k);
    rank2 += dj_less(dk, jk, dme, jme) ? 1 : 0;
  }
  if (lane < 16 && rank2 < 4) {
    subsets[row * 4 + rank2] = jme;
    orows[row * 4 + rank2] = (float)row;
    osubs[row * 4 + rank2] = (float)jme;
  }
}

// ---------------- gather + mean/max pool -> h0 (f16) ----------------
__global__ __launch_bounds__(128) void pool_kernel(const float* __restrict__ x,
                                                   const int* __restrict__ subsets,
                                                   _Float16* __restrict__ h0) {
  int i = blockIdx.x, t = threadIdx.x;
  int s0 = subsets[i * 4 + 0];
  int s1 = subsets[i * 4 + 1];
  int s2 = subsets[i * 4 + 2];
  int s3 = subsets[i * 4 + 3];
  int c = t * 4;
  float4 z0 = *reinterpret_cast<const float4*>(&x[(size_t)s0 * DIM + c]);
  float4 z1 = *reinterpret_cast<const float4*>(&x[(size_t)s1 * DIM + c]);
  float4 z2 = *reinterpret_cast<const float4*>(&x[(size_t)s2 * DIM + c]);
  float4 z3 = *reinterpret_cast<const float4*>(&x[(size_t)s3 * DIM + c]);
  f16x4 mu, mx;
  mu[0] = (_Float16)((z0.x + z1.x + z2.x + z3.x) * 0.25f);
  mu[1] = (_Float16)((z0.y + z1.y + z2.y + z3.y) * 0.25f);
  mu[2] = (_Float16)((z0.z + z1.z + z2.z + z3.z) * 0.25f);
  mu[3] = (_Float16)((z0.w + z1.w + z2.w + z3.w) * 0.25f);
  mx[0] = (_Float16)fmaxf(fmaxf(z0.x, z1.x), fmaxf(z2.x, z3.x));
  mx[1] = (_Float16)fmaxf(fmaxf(z0.y, z1.y), fmaxf(z2.y, z3.y));
  mx[2] = (_Float16)fmaxf(fmaxf(z0.z, z1.z), fmaxf(z2.z, z3.z));
  mx[3] = (_Float16)fmaxf(fmaxf(z0.w, z1.w), fmaxf(z2.w, z3.w));
  *reinterpret_cast<f16x4*>(&h0[(size_t)i * HID + c]) = mu;
  *reinterpret_cast<f16x4*>(&h0[(size_t)i * HID + DIM + c]) = mx;
}

// ---------------- f16 MFMA GEMM: out = act(A @ W^T + bias) ----------------
__global__ __launch_bounds__(256, 2) void gemm_mfma_kernel(const _Float16* __restrict__ A,
                                                           const _Float16* __restrict__ W,
                                                           const float* __restrict__ bias,
                                                           _Float16* __restrict__ out16,
                                                           float* __restrict__ out32,
                                                           int act) {
  __shared__ __align__(16) char smem[16384];
  const int tid = threadIdx.x;
  const int lane = tid & 63;
  const int w = tid >> 6;
  const int wm = w >> 1, wn = w & 1;
  const int row0 = blockIdx.x * 128;
  const int col0 = blockIdx.y * 128;

  int a_off[4], b_off[4];
#pragma unroll
  for (int m = 0; m < 4; ++m) {
    int r = wm * 64 + m * 16 + (lane & 15);
    a_off[m] = r * 64 + (((lane >> 4) ^ S_SWZ(r)) * 16);
  }
#pragma unroll
  for (int n = 0; n < 4; ++n) {
    int r = wn * 64 + n * 16 + (lane & 15);
    b_off[n] = r * 64 + (((lane >> 4) ^ S_SWZ(r)) * 16);
  }

  int goff[2], wb[2];
#pragma unroll
  for (int h = 0; h < 2; ++h) {
    int i = h * 256 + tid;
    int r = i >> 2, cs = i & 3;
    int c = cs ^ S_SWZ(r);
    goff[h] = r * HID + c * 8;
    wb[h] = h * 4096 + w * 1024;
  }

  const _Float16* arow = A + (size_t)row0 * HID;
  const _Float16* brow = W + (size_t)col0 * HID;

  f32x4 acc[4][4];
#pragma unroll
  for (int m = 0; m < 4; ++m)
#pragma unroll
    for (int n = 0; n < 4; ++n) acc[m][n] = (f32x4)0.0f;

#pragma unroll 1
  for (int kt = 0; kt < 32; ++kt) {
    __syncthreads();
#pragma unroll
    for (int h = 0; h < 2; ++h) {
      int go = goff[h] + kt * 32;
      gload_lds16(arow + go, smem + 0 + wb[h]);
      gload_lds16(brow + go, smem + 8192 + wb[h]);
    }
    __syncthreads();

    f16x8 bf[4];
#pragma unroll
    for (int n = 0; n < 4; ++n) bf[n] = *(const f16x8*)(smem + 8192 + b_off[n]);
#pragma unroll
    for (int m = 0; m < 4; ++m) {
      f16x8 af = *(const f16x8*)(smem + 0 + a_off[m]);
#pragma unroll
      for (int n = 0; n < 4; ++n)
        acc[m][n] = __builtin_amdgcn_mfma_f32_16x16x32_f16(af, bf[n], acc[m][n], 0, 0, 0);
    }
  }

  float bv[4];
#pragma unroll
  for (int n = 0; n < 4; ++n) bv[n] = bias[col0 + wn * 64 + n * 16 + (lane & 15)];

#pragma unroll
  for (int m = 0; m < 4; ++m)
#pragma unroll
    for (int n = 0; n < 4; ++n) {
      int cl = col0 + wn * 64 + n * 16 + (lane & 15);
#pragma unroll
      for (int j = 0; j < 4; ++j) {
        int rl = row0 + wm * 64 + m * 16 + ((lane >> 4) << 2) + j;
        float v = acc[m][n][j] + bv[n];
        if (act) {
          if (v < 0.0f) v *= 0.01f;
          out16[(size_t)rl * HID + cl] = (_Float16)v;
        } else {
          out32[(size_t)rl * HID + cl] = v;
        }
      }
    }
}

// ---------------- final elementwise + entropy partial sums ----------------
__global__ __launch_bounds__(256) void outgen_kernel(const float* __restrict__ x,
                                                     const float* __restrict__ h2,
                                                     const float* __restrict__ eps,
                                                     float* __restrict__ xout,
                                                     float* __restrict__ partials) {
  int tid = threadIdx.x;
  int gid = blockIdx.x * 256 + tid;
  size_t base = (size_t)gid * 4;
  int i = (int)(base >> 9);
  int c = (int)(base & 511);
  float4 xv = *reinterpret_cast<const float4*>(&x[base]);
  float4 ev = *reinterpret_cast<const float4*>(&eps[base]);
  float4 mu = *reinterpret_cast<const float4*>(&h2[(size_t)i * HID + c]);
  float4 hs = *reinterpret_cast<const float4*>(&h2[(size_t)i * HID + DIM + c]);
  float4 xo;
  xo.x = xv.x + mu.x + expf(0.5f * hs.x) * ev.x;
  xo.y = xv.y + mu.y + expf(0.5f * hs.y) * ev.y;
  xo.z = xv.z + mu.z + expf(0.5f * hs.z) * ev.z;
  xo.w = xv.w + mu.w + expf(0.5f * hs.w) * ev.w;
  *reinterpret_cast<float4*>(&xout[base]) = xo;
  float lsum = hs.x + hs.y + hs.z + hs.w;
  for (int off = 32; off > 0; off >>= 1) lsum += __shfl_down(lsum, off);
  __shared__ float red[4];
  if ((tid & 63) == 0) red[tid >> 6] = lsum;
  __syncthreads();
  if (tid == 0) partials[blockIdx.x] = red[0] + red[1] + red[2] + red[3];
}

__global__ __launch_bounds__(256) void entfin_kernel(const float* __restrict__ partials,
                                                     float* __restrict__ ent) {
  int t = threadIdx.x;
  float s = 0.0f;
  for (int q = 0; q < 16; ++q) s += partials[t + 256 * q];
  for (int off = 32; off > 0; off >>= 1) s += __shfl_down(s, off);
  __shared__ float red[4];
  if ((t & 63) == 0) red[t >> 6] = s;
  __syncthreads();
  if (t == 0)
    ent[0] = 0.5f + 0.9189385332046727f +
             0.5f * (red[0] + red[1] + red[2] + red[3]) / (8192.0f * 512.0f);
}

extern "C" void kernel_launch(void* const* d_in, const int* in_sizes, int n_in,
                              void* d_out, int out_size, void* d_ws, size_t ws_size,
                              hipStream_t stream) {
  const float* x = (const float*)d_in[0];
  const float* W1 = (const float*)d_in[1];
  const float* b1 = (const float*)d_in[2];
  const float* W2 = (const float*)d_in[3];
  const float* b2 = (const float*)d_in[4];
  const float* eps = (const float*)d_in[5];

  float* out = (float*)d_out;
  float* ws = (float*)d_ws;

  // workspace layout (float offsets)
  float* sq = ws;                                   // 8192
  int* subsets = (int*)(ws + 8192);                 // 32768 ints
  unsigned int* cand = (unsigned int*)(ws + 40960); // 8192*64 u32 (2 MB)
  float* partials = ws + 565248;                    // 4096
  float* h2 = ws + 1048576;                         // 8192*1024 f32
  _Float16* xh = (_Float16*)(ws + 9437184);         // 8192*512 halves (dead after dist)
  _Float16* h0f = (_Float16*)(ws + 9437184);        // 8192*1024 halves (overlaps xh)
  _Float16* h1f = (_Float16*)(ws + 13631488);       // 8192*1024 halves
  _Float16* W1f = (_Float16*)(ws + 17825792);       // 1024*1024 halves
  _Float16* W2f = (_Float16*)(ws + 18350080);       // 1024*1024 halves

  float* xout = out;
  float* ent = out + (size_t)N_ROWS * DIM;
  float* orows = ent + 1;
  float* osubs = orows + (size_t)N_ROWS * 4;

  tof16_rowsq_kernel<<<4096, 256, 0, stream>>>(x, xh, sq);
  f32tof16_kernel<<<1024, 256, 0, stream>>>(W1, W1f);
  f32tof16_kernel<<<1024, 256, 0, stream>>>(W2, W2f);
  dist_top8_mfma<<<dim3(64, 8), 256, 0, stream>>>(xh, sq, cand);
  rescore_kernel<<<N_ROWS, 64, 0, stream>>>(x, sq, cand, subsets, orows, osubs);
  pool_kernel<<<N_ROWS, 128, 0, stream>>>(x, subsets, h0f);
  gemm_mfma_kernel<<<dim3(64, 8), 256, 0, stream>>>(h0f, W1f, b1, h1f, (float*)0, 1);
  gemm_mfma_kernel<<<dim3(64, 8), 256, 0, stream>>>(h1f, W2f, b2, (_Float16*)0, h2, 0);
  outgen_kernel<<<4096, 256, 0, stream>>>(x, h2, eps, xout, partials);
  entfin_kernel<<<1, 256, 0, stream>>>(partials, ent);
}

// Round 5
// 206.812 us; speedup vs baseline: 10.1685x; 1.4325x over previous
//
#include <hip/hip_runtime.h>
#include <math.h>

#define N_ROWS 8192
#define DIM 512
#define HID 1024
#define NSPLIT 16
#define SPLITC 512
#define NCT 4

typedef _Float16 f16x8 __attribute__((ext_vector_type(8)));
typedef _Float16 f16x4 __attribute__((ext_vector_type(4)));
typedef float f32x4 __attribute__((ext_vector_type(4)));

__device__ __forceinline__ bool dj_less(float d1, int j1, float d2, int j2) {
  return (d1 < d2) || (d1 == d2 && j1 < j2);
}
__device__ __forceinline__ unsigned umin32(unsigned a, unsigned b) { return a < b ? a : b; }
__device__ __forceinline__ unsigned umax32(unsigned a, unsigned b) { return a > b ? a : b; }

__device__ __forceinline__ void gload_lds16(const void* g, void* s) {
  __builtin_amdgcn_global_load_lds((const __attribute__((address_space(1))) void*)g,
                                   (__attribute__((address_space(3))) void*)s, 16, 0, 0);
}

#define S_SWZ(r) ((((r) & 3) ^ (((r) >> 2) & 3)))

// branchless sorted-insert of x into ascending K[0..3]
#define INS4(K, xin)                                   \
  {                                                    \
    unsigned xx = (xin), t;                            \
    t = umin32(K[0], xx); xx = umax32(K[0], xx); K[0] = t; \
    t = umin32(K[1], xx); xx = umax32(K[1], xx); K[1] = t; \
    t = umin32(K[2], xx); xx = umax32(K[2], xx); K[2] = t; \
    K[3] = umin32(K[3], xx);                           \
  }

// ---------------- fp32 -> f16 + fused row sq-norms ----------------
__global__ __launch_bounds__(256) void tof16_rowsq_kernel(const float* __restrict__ x,
                                                          _Float16* __restrict__ xh,
                                                          float* __restrict__ sq) {
  int tid = threadIdx.x;
  int g = blockIdx.x * 256 + tid;
  float4 v = reinterpret_cast<const float4*>(x)[g];
  f16x4 hv = {(_Float16)v.x, (_Float16)v.y, (_Float16)v.z, (_Float16)v.w};
  reinterpret_cast<f16x4*>(xh)[g] = hv;
  float s = v.x * v.x + v.y * v.y + v.z * v.z + v.w * v.w;
  for (int off = 32; off > 0; off >>= 1) s += __shfl_down(s, off);
  __shared__ float red[4];
  if ((tid & 63) == 0) red[tid >> 6] = s;
  __syncthreads();
  if (tid == 0) sq[blockIdx.x * 2] = red[0] + red[1];
  if (tid == 128) sq[blockIdx.x * 2 + 1] = red[2] + red[3];
}

// ---------------- f32 -> f16 (weights) ----------------
__global__ __launch_bounds__(256) void f32tof16_kernel(const float* __restrict__ in,
                                                       _Float16* __restrict__ out) {
  int g = blockIdx.x * 256 + threadIdx.x;
  float4 v = reinterpret_cast<const float4*>(in)[g];
  f16x4 h = {(_Float16)v.x, (_Float16)v.y, (_Float16)v.z, (_Float16)v.w};
  reinterpret_cast<f16x4*>(out)[g] = h;
}

// ---------------- f16 MFMA distance + per-row candidate keys (16 j-splits) ----------------
// grid (64, 16), block 256 (4 waves 2x2). Tile 128x128, BK=32, double-buffered staging.
// key = (bits(d~ + 1024) & 0xFFFFE000) | col   (positive float -> monotone u32)
__global__ __launch_bounds__(256, 3) void dist_cand_mfma(const _Float16* __restrict__ xh,
                                                         const float* __restrict__ sq,
                                                         unsigned int* __restrict__ cand) {
  // LDS: buf0 [0,16K) buf1 [16K,32K) (each: A 8K + B 8K); DkA [64][36] @32768; DkB @42, total 51200
  __shared__ __align__(16) char smem[51200];
  unsigned* DkA = (unsigned*)(smem + 32768);
  unsigned* DkB = (unsigned*)(smem + 41984);
  const int tid = threadIdx.x;
  const int lane = tid & 63;
  const int w = tid >> 6;
  const int wm = w >> 1, wn = w & 1;
  const int row0 = blockIdx.x * 128;
  const int js = blockIdx.y;

  int a_off[4], b_off[4];
#pragma unroll
  for (int m = 0; m < 4; ++m) {
    int r = wm * 64 + m * 16 + (lane & 15);
    a_off[m] = r * 64 + (((lane >> 4) ^ S_SWZ(r)) * 16);
  }
#pragma unroll
  for (int n = 0; n < 4; ++n) {
    int r = wn * 64 + n * 16 + (lane & 15);
    b_off[n] = r * 64 + (((lane >> 4) ^ S_SWZ(r)) * 16);
  }

  int goff[2], wb[2];
#pragma unroll
  for (int h = 0; h < 2; ++h) {
    int i = h * 256 + tid;
    int r = i >> 2, cs = i & 3;
    int c = cs ^ S_SWZ(r);
    goff[h] = r * 512 + c * 8;   // f16 elements
    wb[h] = h * 4096 + w * 1024; // bytes, wave-uniform
  }

  const int sr = tid >> 2;  // scan row 0..63
  const int sc = tid & 3;   // scan class 0..3
  const int slot = wn * 16 + (lane & 15);

  unsigned keys[2][4];
#pragma unroll
  for (int p = 0; p < 2; ++p)
#pragma unroll
    for (int q = 0; q < 4; ++q) keys[p][q] = 0xFFFFFFFFu;

  const _Float16* arow = xh + (size_t)row0 * DIM;

  f32x4 acc[4][4];

  auto stage = [&](int b, const _Float16* br, int kt) {
#pragma unroll
    for (int h = 0; h < 2; ++h) {
      int go = goff[h] + kt * 32;
      gload_lds16(arow + go, smem + b * 16384 + wb[h]);
      gload_lds16(br + go, smem + b * 16384 + 8192 + wb[h]);
    }
  };
  auto compute = [&](int b) {
    f16x8 bf[4];
#pragma unroll
    for (int n = 0; n < 4; ++n) bf[n] = *(const f16x8*)(smem + b * 16384 + 8192 + b_off[n]);
#pragma unroll
    for (int m = 0; m < 4; ++m) {
      f16x8 af = *(const f16x8*)(smem + b * 16384 + a_off[m]);
#pragma unroll
      for (int n = 0; n < 4; ++n)
        acc[m][n] = __builtin_amdgcn_mfma_f32_16x16x32_f16(af, bf[n], acc[m][n], 0, 0, 0);
    }
  };

  // prologue: stage ct=0, kt=0 into buf0
  stage(0, xh + (size_t)(js * SPLITC) * DIM, 0);
  __syncthreads();

#pragma unroll 1
  for (int ct = 0; ct < NCT; ++ct) {
    const int c0 = js * SPLITC + ct * 128;
    const _Float16* brow = xh + (size_t)c0 * DIM;
#pragma unroll
    for (int m = 0; m < 4; ++m)
#pragma unroll
      for (int n = 0; n < 4; ++n) acc[m][n] = (f32x4)0.0f;

#pragma unroll 1
    for (int k = 0; k < 8; ++k) {
      stage(1, brow, 2 * k + 1);
      compute(0);
      __syncthreads();
      if (k < 7) stage(0, brow, 2 * k + 2);
      compute(1);
      __syncthreads();
    }

    // prefetch next ct's kt=0 into buf0 (drained by epilogue barriers)
    stage(0, xh + (size_t)(js * SPLITC + ((ct + 1) & (NCT - 1)) * 128) * DIM, 0);

    float sqjb[4];
#pragma unroll
    for (int n = 0; n < 4; ++n) sqjb[n] = sq[c0 + wn * 64 + n * 16 + (lane & 15)] + 1024.0f;

#pragma unroll
    for (int p = 0; p < 2; ++p) {
      if (wm == p) {
#pragma unroll
        for (int m = 0; m < 4; ++m)
#pragma unroll
          for (int j = 0; j < 4; ++j) {
            int rl = m * 16 + ((lane >> 4) << 2) + j;
            unsigned u[4];
#pragma unroll
            for (int n = 0; n < 4; ++n) {
              float v = fmaf(-2.0f, acc[m][n][j], sqjb[n]);
              u[n] = (__float_as_uint(v) & 0xFFFFE000u) |
                     (unsigned)(c0 + wn * 64 + n * 16 + (lane & 15));
            }
            unsigned lo01 = umin32(u[0], u[1]), hi01 = umax32(u[0], u[1]);
            unsigned lo23 = umin32(u[2], u[3]), hi23 = umax32(u[2], u[3]);
            DkA[rl * 36 + slot] = umin32(lo01, lo23);
            DkB[rl * 36 + slot] = umin32(umax32(lo01, lo23), umin32(hi01, hi23));
          }
      }
      __syncthreads();
      {
        const uint4* pa = (const uint4*)&DkA[sr * 36 + sc * 8];
        const uint4* pb = (const uint4*)&DkB[sr * 36 + sc * 8];
        uint4 a0 = pa[0], a1 = pa[1], b0 = pb[0], b1 = pb[1];
        INS4(keys[p], a0.x); INS4(keys[p], a0.y); INS4(keys[p], a0.z); INS4(keys[p], a0.w);
        INS4(keys[p], a1.x); INS4(keys[p], a1.y); INS4(keys[p], a1.z); INS4(keys[p], a1.w);
        INS4(keys[p], b0.x); INS4(keys[p], b0.y); INS4(keys[p], b0.z); INS4(keys[p], b0.w);
        INS4(keys[p], b1.x); INS4(keys[p], b1.y); INS4(keys[p], b1.z); INS4(keys[p], b1.w);
      }
      __syncthreads();
    }
  }

  // write candidates: 4 sorted keys per (row, scan-class) per split
#pragma unroll
  for (int p = 0; p < 2; ++p) {
    int row = row0 + p * 64 + sr;
    uint4 o;
    o.x = keys[p][0]; o.y = keys[p][1]; o.z = keys[p][2]; o.w = keys[p][3];
    *reinterpret_cast<uint4*>(&cand[(size_t)row * 256 + js * 16 + sc * 4]) = o;
  }
}

// ---------------- rescore: merge 256 cands -> key-top16 -> exact fp32 top-4 ----------------
__global__ __launch_bounds__(64) void rescore_kernel(const float* __restrict__ x,
                                                     const float* __restrict__ sq,
                                                     const unsigned int* __restrict__ cand,
                                                     int* __restrict__ subsets,
                                                     float* __restrict__ orows,
                                                     float* __restrict__ osubs) {
  const int row = blockIdx.x;
  const int lane = threadIdx.x;
  uint4 q = *reinterpret_cast<const uint4*>(&cand[(size_t)row * 256 + lane * 4]);
  unsigned cur = q.x, c1 = q.y, c2 = q.z, c3 = q.w;
  unsigned myj = 0;
#pragma unroll 1
  for (int r = 0; r < 16; ++r) {
    unsigned mn = cur;
#pragma unroll
    for (int off = 32; off > 0; off >>= 1)
      mn = umin32(mn, (unsigned)__shfl_xor((int)mn, off));
    if (cur == mn) { cur = c1; c1 = c2; c2 = c3; c3 = 0xFFFFFFFFu; }
    if (lane == r) myj = mn & 0x1FFFu;
  }

  const float4* xi = reinterpret_cast<const float4*>(x + (size_t)row * DIM);
  float4 xa = xi[lane];
  float4 xb = xi[lane + 64];
  float sqi = sq[row];

  float dme = 0.0f;
  int jme = 0;
#pragma unroll 1
  for (int c = 0; c < 16; ++c) {
    int j = __shfl((int)myj, c);
    const float4* xj = reinterpret_cast<const float4*>(x + (size_t)j * DIM);
    float4 ya = xj[lane];
    float4 yb = xj[lane + 64];
    float dot = xa.x * ya.x + xa.y * ya.y + xa.z * ya.z + xa.w * ya.w +
                xb.x * yb.x + xb.y * yb.y + xb.z * yb.z + xb.w * yb.w;
#pragma unroll
    for (int off = 32; off > 0; off >>= 1) dot += __shfl_xor(dot, off);
    float d = sqi + sq[j] - 2.0f * dot;
    if (lane == c) { dme = d; jme = j; }
  }

  int rank2 = 0;
#pragma unroll
  for (int k = 0; k < 16; ++k) {
    float dk = __shfl(dme, k);
    int jk = __shfl(jme, k);
    rank2 += dj_less(dk, jk, dme, jme) ? 1 : 0;
  }
  if (lane < 16 && rank2 < 4) {
    subsets[row * 4 + rank2] = jme;
    orows[row * 4 + rank2] = (float)row;
    osubs[row * 4 + rank2] = (float)jme;
  }
}

// ---------------- gather + mean/max pool -> h0 (f16) ----------------
__global__ __launch_bounds__(128) void pool_kernel(const float* __restrict__ x,
                                                   const int* __restrict__ subsets,
                                                   _Float16* __restrict__ h0) {
  int i = blockIdx.x, t = threadIdx.x;
  int s0 = subsets[i * 4 + 0];
  int s1 = subsets[i * 4 + 1];
  int s2 = subsets[i * 4 + 2];
  int s3 = subsets[i * 4 + 3];
  int c = t * 4;
  float4 z0 = *reinterpret_cast<const float4*>(&x[(size_t)s0 * DIM + c]);
  float4 z1 = *reinterpret_cast<const float4*>(&x[(size_t)s1 * DIM + c]);
  float4 z2 = *reinterpret_cast<const float4*>(&x[(size_t)s2 * DIM + c]);
  float4 z3 = *reinterpret_cast<const float4*>(&x[(size_t)s3 * DIM + c]);
  f16x4 mu, mx;
  mu[0] = (_Float16)((z0.x + z1.x + z2.x + z3.x) * 0.25f);
  mu[1] = (_Float16)((z0.y + z1.y + z2.y + z3.y) * 0.25f);
  mu[2] = (_Float16)((z0.z + z1.z + z2.z + z3.z) * 0.25f);
  mu[3] = (_Float16)((z0.w + z1.w + z2.w + z3.w) * 0.25f);
  mx[0] = (_Float16)fmaxf(fmaxf(z0.x, z1.x), fmaxf(z2.x, z3.x));
  mx[1] = (_Float16)fmaxf(fmaxf(z0.y, z1.y), fmaxf(z2.y, z3.y));
  mx[2] = (_Float16)fmaxf(fmaxf(z0.z, z1.z), fmaxf(z2.z, z3.z));
  mx[3] = (_Float16)fmaxf(fmaxf(z0.w, z1.w), fmaxf(z2.w, z3.w));
  *reinterpret_cast<f16x4*>(&h0[(size_t)i * HID + c]) = mu;
  *reinterpret_cast<f16x4*>(&h0[(size_t)i * HID + DIM + c]) = mx;
}

// ---------------- f16 MFMA GEMM (double-buffered): out = act(A @ W^T + bias) ----------------
__global__ __launch_bounds__(256, 2) void gemm_mfma_kernel(const _Float16* __restrict__ A,
                                                           const _Float16* __restrict__ W,
                                                           const float* __restrict__ bias,
                                                           _Float16* __restrict__ out16,
                                                           float* __restrict__ out32,
                                                           int act) {
  __shared__ __align__(16) char smem[32768];  // 2 buffers x (A 8K + B 8K)
  const int tid = threadIdx.x;
  const int lane = tid & 63;
  const int w = tid >> 6;
  const int wm = w >> 1, wn = w & 1;
  const int row0 = blockIdx.x * 128;
  const int col0 = blockIdx.y * 128;

  int a_off[4], b_off[4];
#pragma unroll
  for (int m = 0; m < 4; ++m) {
    int r = wm * 64 + m * 16 + (lane & 15);
    a_off[m] = r * 64 + (((lane >> 4) ^ S_SWZ(r)) * 16);
  }
#pragma unroll
  for (int n = 0; n < 4; ++n) {
    int r = wn * 64 + n * 16 + (lane & 15);
    b_off[n] = r * 64 + (((lane >> 4) ^ S_SWZ(r)) * 16);
  }

  int goff[2], wb[2];
#pragma unroll
  for (int h = 0; h < 2; ++h) {
    int i = h * 256 + tid;
    int r = i >> 2, cs = i & 3;
    int c = cs ^ S_SWZ(r);
    goff[h] = r * HID + c * 8;
    wb[h] = h * 4096 + w * 1024;
  }

  const _Float16* arow = A + (size_t)row0 * HID;
  const _Float16* brow = W + (size_t)col0 * HID;

  f32x4 acc[4][4];
#pragma unroll
  for (int m = 0; m < 4; ++m)
#pragma unroll
    for (int n = 0; n < 4; ++n) acc[m][n] = (f32x4)0.0f;

  auto stage = [&](int b, int kt) {
#pragma unroll
    for (int h = 0; h < 2; ++h) {
      int go = goff[h] + kt * 32;
      gload_lds16(arow + go, smem + b * 16384 + wb[h]);
      gload_lds16(brow + go, smem + b * 16384 + 8192 + wb[h]);
    }
  };
  auto compute = [&](int b) {
    f16x8 bf[4];
#pragma unroll
    for (int n = 0; n < 4; ++n) bf[n] = *(const f16x8*)(smem + b * 16384 + 8192 + b_off[n]);
#pragma unroll
    for (int m = 0; m < 4; ++m) {
      f16x8 af = *(const f16x8*)(smem + b * 16384 + a_off[m]);
#pragma unroll
      for (int n = 0; n < 4; ++n)
        acc[m][n] = __builtin_amdgcn_mfma_f32_16x16x32_f16(af, bf[n], acc[m][n], 0, 0, 0);
    }
  };

  stage(0, 0);
  __syncthreads();
#pragma unroll 1
  for (int k = 0; k < 16; ++k) {
    stage(1, 2 * k + 1);
    compute(0);
    __syncthreads();
    if (k < 15) stage(0, 2 * k + 2);
    compute(1);
    __syncthreads();
  }

  float bv[4];
#pragma unroll
  for (int n = 0; n < 4; ++n) bv[n] = bias[col0 + wn * 64 + n * 16 + (lane & 15)];

#pragma unroll
  for (int m = 0; m < 4; ++m)
#pragma unroll
    for (int n = 0; n < 4; ++n) {
      int cl = col0 + wn * 64 + n * 16 + (lane & 15);
#pragma unroll
      for (int j = 0; j < 4; ++j) {
        int rl = row0 + wm * 64 + m * 16 + ((lane >> 4) << 2) + j;
        float v = acc[m][n][j] + bv[n];
        if (act) {
          if (v < 0.0f) v *= 0.01f;
          out16[(size_t)rl * HID + cl] = (_Float16)v;
        } else {
          out32[(size_t)rl * HID + cl] = v;
        }
      }
    }
}

// ---------------- final elementwise + entropy partial sums ----------------
__global__ __launch_bounds__(256) void outgen_kernel(const float* __restrict__ x,
                                                     const float* __restrict__ h2,
                                                     const float* __restrict__ eps,
                                                     float* __restrict__ xout,
                                                     float* __restrict__ partials) {
  int tid = threadIdx.x;
  int gid = blockIdx.x * 256 + tid;
  size_t base = (size_t)gid * 4;
  int i = (int)(base >> 9);
  int c = (int)(base & 511);
  float4 xv = *reinterpret_cast<const float4*>(&x[base]);
  float4 ev = *reinterpret_cast<const float4*>(&eps[base]);
  float4 mu = *reinterpret_cast<const float4*>(&h2[(size_t)i * HID + c]);
  float4 hs = *reinterpret_cast<const float4*>(&h2[(size_t)i * HID + DIM + c]);
  float4 xo;
  xo.x = xv.x + mu.x + expf(0.5f * hs.x) * ev.x;
  xo.y = xv.y + mu.y + expf(0.5f * hs.y) * ev.y;
  xo.z = xv.z + mu.z + expf(0.5f * hs.z) * ev.z;
  xo.w = xv.w + mu.w + expf(0.5f * hs.w) * ev.w;
  *reinterpret_cast<float4*>(&xout[base]) = xo;
  float lsum = hs.x + hs.y + hs.z + hs.w;
  for (int off = 32; off > 0; off >>= 1) lsum += __shfl_down(lsum, off);
  __shared__ float red[4];
  if ((tid & 63) == 0) red[tid >> 6] = lsum;
  __syncthreads();
  if (tid == 0) partials[blockIdx.x] = red[0] + red[1] + red[2] + red[3];
}

__global__ __launch_bounds__(256) void entfin_kernel(const float* __restrict__ partials,
                                                     float* __restrict__ ent) {
  int t = threadIdx.x;
  float s = 0.0f;
  for (int q = 0; q < 16; ++q) s += partials[t + 256 * q];
  for (int off = 32; off > 0; off >>= 1) s += __shfl_down(s, off);
  __shared__ float red[4];
  if ((t & 63) == 0) red[t >> 6] = s;
  __syncthreads();
  if (t == 0)
    ent[0] = 0.5f + 0.9189385332046727f +
             0.5f * (red[0] + red[1] + red[2] + red[3]) / (8192.0f * 512.0f);
}

extern "C" void kernel_launch(void* const* d_in, const int* in_sizes, int n_in,
                              void* d_out, int out_size, void* d_ws, size_t ws_size,
                              hipStream_t stream) {
  const float* x = (const float*)d_in[0];
  const float* W1 = (const float*)d_in[1];
  const float* b1 = (const float*)d_in[2];
  const float* W2 = (const float*)d_in[3];
  const float* b2 = (const float*)d_in[4];
  const float* eps = (const float*)d_in[5];

  float* out = (float*)d_out;
  float* ws = (float*)d_ws;

  // workspace layout (float offsets)
  float* sq = ws;                                   // [0, 8192)
  int* subsets = (int*)(ws + 8192);                 // [8192, 40960)
  float* partials = ws + 40960;                     // [40960, 45056)
  unsigned int* cand = (unsigned int*)(ws + 65536); // [65536, 2162688) u32 8MB (dead before h2 written)
  float* h2 = ws + 65536;                           // [65536, 8454144) f32, overlaps cand
  _Float16* xh = (_Float16*)(ws + 8454144);         // 8192*512 halves (dead after dist)
  _Float16* h0f = (_Float16*)(ws + 8454144);        // 8192*1024 halves, overlaps xh
  _Float16* h1f = (_Float16*)(ws + 12648448);       // 8192*1024 halves
  _Float16* W1f = (_Float16*)(ws + 16842752);       // 1024*1024 halves
  _Float16* W2f = (_Float16*)(ws + 17367040);       // 1024*1024 halves

  float* xout = out;
  float* ent = out + (size_t)N_ROWS * DIM;
  float* orows = ent + 1;
  float* osubs = orows + (size_t)N_ROWS * 4;

  tof16_rowsq_kernel<<<4096, 256, 0, stream>>>(x, xh, sq);
  f32tof16_kernel<<<1024, 256, 0, stream>>>(W1, W1f);
  f32tof16_kernel<<<1024, 256, 0, stream>>>(W2, W2f);
  dist_cand_mfma<<<dim3(64, NSPLIT), 256, 0, stream>>>(xh, sq, cand);
  rescore_kernel<<<N_ROWS, 64, 0, stream>>>(x, sq, cand, subsets, orows, osubs);
  pool_kernel<<<N_ROWS, 128, 0, stream>>>(x, subsets, h0f);
  gemm_mfma_kernel<<<dim3(64, 8), 256, 0, stream>>>(h0f, W1f, b1, h1f, (float*)0, 1);
  gemm_mfma_kernel<<<dim3(64, 8), 256, 0, stream>>>(h1f, W2f, b2, (_Float16*)0, h2, 0);
  outgen_kernel<<<4096, 256, 0, stream>>>(x, h2, eps, xout, partials);
  entfin_kernel<<<1, 256, 0, stream>>>(partials, ent);
}

// Round 6
// 186.907 us; speedup vs baseline: 11.2514x; 1.1065x over previous
//
#include <hip/hip_runtime.h>
#include <math.h>

#define N_ROWS 8192
#define DIM 512
#define HID 1024
#define NSPLIT 16
#define SPLITC 512
#define NCT 4

typedef _Float16 f16x8 __attribute__((ext_vector_type(8)));
typedef _Float16 f16x4 __attribute__((ext_vector_type(4)));
typedef float f32x4 __attribute__((ext_vector_type(4)));

__device__ __forceinline__ bool dj_less(float d1, int j1, float d2, int j2) {
  return (d1 < d2) || (d1 == d2 && j1 < j2);
}
__device__ __forceinline__ unsigned umin32(unsigned a, unsigned b) { return a < b ? a : b; }
__device__ __forceinline__ unsigned umax32(unsigned a, unsigned b) { return a > b ? a : b; }

__device__ __forceinline__ void gload_lds16(const void* g, void* s) {
  __builtin_amdgcn_global_load_lds((const __attribute__((address_space(1))) void*)g,
                                   (__attribute__((address_space(3))) void*)s, 16, 0, 0);
}

#define S_SWZ(r) ((((r) & 3) ^ (((r) >> 2) & 3)))

// branchless sorted-insert of x into ascending K[0..3]
#define INS4(K, xin)                                   \
  {                                                    \
    unsigned xx = (xin), t;                            \
    t = umin32(K[0], xx); xx = umax32(K[0], xx); K[0] = t; \
    t = umin32(K[1], xx); xx = umax32(K[1], xx); K[1] = t; \
    t = umin32(K[2], xx); xx = umax32(K[2], xx); K[2] = t; \
    K[3] = umin32(K[3], xx);                           \
  }

// ---------------- fused converts: x->f16 + row sq-norms, W1->f16, W2->f16 ----------------
__global__ __launch_bounds__(256) void convert_kernel(const float* __restrict__ x,
                                                      const float* __restrict__ W1,
                                                      const float* __restrict__ W2,
                                                      _Float16* __restrict__ xh,
                                                      _Float16* __restrict__ W1f,
                                                      _Float16* __restrict__ W2f,
                                                      float* __restrict__ sq) {
  int bid = blockIdx.x;
  int tid = threadIdx.x;
  if (bid < 4096) {
    int g = bid * 256 + tid;
    float4 v = reinterpret_cast<const float4*>(x)[g];
    f16x4 hv = {(_Float16)v.x, (_Float16)v.y, (_Float16)v.z, (_Float16)v.w};
    reinterpret_cast<f16x4*>(xh)[g] = hv;
    float s = v.x * v.x + v.y * v.y + v.z * v.z + v.w * v.w;
    for (int off = 32; off > 0; off >>= 1) s += __shfl_down(s, off);
    __shared__ float red[4];
    if ((tid & 63) == 0) red[tid >> 6] = s;
    __syncthreads();
    if (tid == 0) sq[bid * 2] = red[0] + red[1];
    if (tid == 128) sq[bid * 2 + 1] = red[2] + red[3];
  } else {
    const float* src = (bid < 5120) ? W1 : W2;
    _Float16* dst = (bid < 5120) ? W1f : W2f;
    int g = ((bid < 5120) ? (bid - 4096) : (bid - 5120)) * 256 + tid;
    float4 v = reinterpret_cast<const float4*>(src)[g];
    f16x4 h = {(_Float16)v.x, (_Float16)v.y, (_Float16)v.z, (_Float16)v.w};
    reinterpret_cast<f16x4*>(dst)[g] = h;
  }
}

// ---------------- f16 MFMA distance + per-row candidate keys (16 j-splits) ----------------
// grid (64, 16), block 256 (4 waves 2x2). Tile 128x128, BK=32, double-buffered staging.
// Dk key planes alias buf1 (epilogue-only lifetime) -> LDS 34816 B -> 4 blocks/CU.
// key = (bits(d~ + 1024) & 0xFFFFE000) | col
__global__ __launch_bounds__(256, 4) void dist_cand_mfma(const _Float16* __restrict__ xh,
                                                         const float* __restrict__ sq,
                                                         unsigned int* __restrict__ cand) {
  // LDS: buf0 [0,16K) buf1 [16K,32K); DkA [64][36] @16384 (over buf1), DkB @25600, end 34816
  __shared__ __align__(16) char smem[34816];
  unsigned* DkA = (unsigned*)(smem + 16384);
  unsigned* DkB = (unsigned*)(smem + 25600);
  const int tid = threadIdx.x;
  const int lane = tid & 63;
  const int w = tid >> 6;
  const int wm = w >> 1, wn = w & 1;
  const int row0 = blockIdx.x * 128;
  const int js = blockIdx.y;

  int a_off[4], b_off[4];
#pragma unroll
  for (int m = 0; m < 4; ++m) {
    int r = wm * 64 + m * 16 + (lane & 15);
    a_off[m] = r * 64 + (((lane >> 4) ^ S_SWZ(r)) * 16);
  }
#pragma unroll
  for (int n = 0; n < 4; ++n) {
    int r = wn * 64 + n * 16 + (lane & 15);
    b_off[n] = r * 64 + (((lane >> 4) ^ S_SWZ(r)) * 16);
  }

  int goff[2], wb[2];
#pragma unroll
  for (int h = 0; h < 2; ++h) {
    int i = h * 256 + tid;
    int r = i >> 2, cs = i & 3;
    int c = cs ^ S_SWZ(r);
    goff[h] = r * 512 + c * 8;   // f16 elements
    wb[h] = h * 4096 + w * 1024; // bytes, wave-uniform
  }

  const int sr = tid >> 2;  // scan row 0..63
  const int sc = tid & 3;   // scan class 0..3
  const int slot = wn * 16 + (lane & 15);

  unsigned keys[2][4];
#pragma unroll
  for (int p = 0; p < 2; ++p)
#pragma unroll
    for (int q = 0; q < 4; ++q) keys[p][q] = 0xFFFFFFFFu;

  const _Float16* arow = xh + (size_t)row0 * DIM;

  f32x4 acc[4][4];

  auto stage = [&](int b, const _Float16* br, int kt) {
#pragma unroll
    for (int h = 0; h < 2; ++h) {
      int go = goff[h] + kt * 32;
      gload_lds16(arow + go, smem + b * 16384 + wb[h]);
      gload_lds16(br + go, smem + b * 16384 + 8192 + wb[h]);
    }
  };
  auto compute = [&](int b) {
    f16x8 bf[4];
#pragma unroll
    for (int n = 0; n < 4; ++n) bf[n] = *(const f16x8*)(smem + b * 16384 + 8192 + b_off[n]);
#pragma unroll
    for (int m = 0; m < 4; ++m) {
      f16x8 af = *(const f16x8*)(smem + b * 16384 + a_off[m]);
#pragma unroll
      for (int n = 0; n < 4; ++n)
        acc[m][n] = __builtin_amdgcn_mfma_f32_16x16x32_f16(af, bf[n], acc[m][n], 0, 0, 0);
    }
  };

  // prologue: stage ct=0, kt=0 into buf0
  stage(0, xh + (size_t)(js * SPLITC) * DIM, 0);
  __syncthreads();

#pragma unroll 1
  for (int ct = 0; ct < NCT; ++ct) {
    const int c0 = js * SPLITC + ct * 128;
    const _Float16* brow = xh + (size_t)c0 * DIM;
#pragma unroll
    for (int m = 0; m < 4; ++m)
#pragma unroll
      for (int n = 0; n < 4; ++n) acc[m][n] = (f32x4)0.0f;

#pragma unroll 1
    for (int k = 0; k < 8; ++k) {
      stage(1, brow, 2 * k + 1);
      compute(0);
      __syncthreads();
      if (k < 7) stage(0, brow, 2 * k + 2);
      compute(1);
      __syncthreads();
    }

    // prefetch next ct's kt=0 into buf0 (drained by epilogue barriers)
    stage(0, xh + (size_t)(js * SPLITC + ((ct + 1) & (NCT - 1)) * 128) * DIM, 0);

    float sqjb[4];
#pragma unroll
    for (int n = 0; n < 4; ++n) sqjb[n] = sq[c0 + wn * 64 + n * 16 + (lane & 15)] + 1024.0f;

#pragma unroll
    for (int p = 0; p < 2; ++p) {
      if (wm == p) {
#pragma unroll
        for (int m = 0; m < 4; ++m)
#pragma unroll
          for (int j = 0; j < 4; ++j) {
            int rl = m * 16 + ((lane >> 4) << 2) + j;
            unsigned u[4];
#pragma unroll
            for (int n = 0; n < 4; ++n) {
              float v = fmaf(-2.0f, acc[m][n][j], sqjb[n]);
              u[n] = (__float_as_uint(v) & 0xFFFFE000u) |
                     (unsigned)(c0 + wn * 64 + n * 16 + (lane & 15));
            }
            unsigned lo01 = umin32(u[0], u[1]), hi01 = umax32(u[0], u[1]);
            unsigned lo23 = umin32(u[2], u[3]), hi23 = umax32(u[2], u[3]);
            DkA[rl * 36 + slot] = umin32(lo01, lo23);
            DkB[rl * 36 + slot] = umin32(umax32(lo01, lo23), umin32(hi01, hi23));
          }
      }
      __syncthreads();
      {
        const uint4* pa = (const uint4*)&DkA[sr * 36 + sc * 8];
        const uint4* pb = (const uint4*)&DkB[sr * 36 + sc * 8];
        uint4 a0 = pa[0], a1 = pa[1], b0 = pb[0], b1 = pb[1];
        INS4(keys[p], a0.x); INS4(keys[p], a0.y); INS4(keys[p], a0.z); INS4(keys[p], a0.w);
        INS4(keys[p], a1.x); INS4(keys[p], a1.y); INS4(keys[p], a1.z); INS4(keys[p], a1.w);
        INS4(keys[p], b0.x); INS4(keys[p], b0.y); INS4(keys[p], b0.z); INS4(keys[p], b0.w);
        INS4(keys[p], b1.x); INS4(keys[p], b1.y); INS4(keys[p], b1.z); INS4(keys[p], b1.w);
      }
      __syncthreads();
    }
  }

  // write candidates: 4 sorted keys per (row, scan-class) per split
#pragma unroll
  for (int p = 0; p < 2; ++p) {
    int row = row0 + p * 64 + sr;
    uint4 o;
    o.x = keys[p][0]; o.y = keys[p][1]; o.z = keys[p][2]; o.w = keys[p][3];
    *reinterpret_cast<uint4*>(&cand[(size_t)row * 256 + js * 16 + sc * 4]) = o;
  }
}

// ---------------- rescore + pool: merge 256 cands -> exact fp32 top-4 -> h0 ----------------
__global__ __launch_bounds__(64) void rescore_pool_kernel(const float* __restrict__ x,
                                                          const float* __restrict__ sq,
                                                          const unsigned int* __restrict__ cand,
                                                          float* __restrict__ orows,
                                                          float* __restrict__ osubs,
                                                          _Float16* __restrict__ h0) {
  const int row = blockIdx.x;
  const int lane = threadIdx.x;
  uint4 q = *reinterpret_cast<const uint4*>(&cand[(size_t)row * 256 + lane * 4]);
  unsigned cur = q.x, c1 = q.y, c2 = q.z, c3 = q.w;
  unsigned myj = 0;
#pragma unroll 1
  for (int r = 0; r < 16; ++r) {
    unsigned mn = cur;
#pragma unroll
    for (int off = 32; off > 0; off >>= 1)
      mn = umin32(mn, (unsigned)__shfl_xor((int)mn, off));
    if (cur == mn) { cur = c1; c1 = c2; c2 = c3; c3 = 0xFFFFFFFFu; }
    if (lane == r) myj = mn & 0x1FFFu;
  }

  const float4* xi = reinterpret_cast<const float4*>(x + (size_t)row * DIM);
  float4 xa = xi[lane];
  float4 xb = xi[lane + 64];
  float sqi = sq[row];

  float dme = 0.0f;
  int jme = 0;
#pragma unroll 1
  for (int c = 0; c < 16; ++c) {
    int j = __shfl((int)myj, c);
    const float4* xj = reinterpret_cast<const float4*>(x + (size_t)j * DIM);
    float4 ya = xj[lane];
    float4 yb = xj[lane + 64];
    float dot = xa.x * ya.x + xa.y * ya.y + xa.z * ya.z + xa.w * ya.w +
                xb.x * yb.x + xb.y * yb.y + xb.z * yb.z + xb.w * yb.w;
#pragma unroll
    for (int off = 32; off > 0; off >>= 1) dot += __shfl_xor(dot, off);
    float d = sqi + sq[j] - 2.0f * dot;
    if (lane == c) { dme = d; jme = j; }
  }

  int rank2 = 0;
#pragma unroll
  for (int k = 0; k < 16; ++k) {
    float dk = __shfl(dme, k);
    int jk = __shfl(jme, k);
    rank2 += dj_less(dk, jk, dme, jme) ? 1 : 0;
  }
  __shared__ int s4[4];
  if (lane < 16 && rank2 < 4) {
    s4[rank2] = jme;
    orows[row * 4 + rank2] = (float)row;
    osubs[row * 4 + rank2] = (float)jme;
  }
  __syncthreads();

  // pooling: 8 cols per lane over the 4 selected rows
  int j0 = s4[0], j1 = s4[1], j2 = s4[2], j3 = s4[3];
  int c = lane * 8;
  float4 z0a = *reinterpret_cast<const float4*>(&x[(size_t)j0 * DIM + c]);
  float4 z0b = *reinterpret_cast<const float4*>(&x[(size_t)j0 * DIM + c + 4]);
  float4 z1a = *reinterpret_cast<const float4*>(&x[(size_t)j1 * DIM + c]);
  float4 z1b = *reinterpret_cast<const float4*>(&x[(size_t)j1 * DIM + c + 4]);
  float4 z2a = *reinterpret_cast<const float4*>(&x[(size_t)j2 * DIM + c]);
  float4 z2b = *reinterpret_cast<const float4*>(&x[(size_t)j2 * DIM + c + 4]);
  float4 z3a = *reinterpret_cast<const float4*>(&x[(size_t)j3 * DIM + c]);
  float4 z3b = *reinterpret_cast<const float4*>(&x[(size_t)j3 * DIM + c + 4]);
  f16x8 mu, mx;
  mu[0] = (_Float16)((z0a.x + z1a.x + z2a.x + z3a.x) * 0.25f);
  mu[1] = (_Float16)((z0a.y + z1a.y + z2a.y + z3a.y) * 0.25f);
  mu[2] = (_Float16)((z0a.z + z1a.z + z2a.z + z3a.z) * 0.25f);
  mu[3] = (_Float16)((z0a.w + z1a.w + z2a.w + z3a.w) * 0.25f);
  mu[4] = (_Float16)((z0b.x + z1b.x + z2b.x + z3b.x) * 0.25f);
  mu[5] = (_Float16)((z0b.y + z1b.y + z2b.y + z3b.y) * 0.25f);
  mu[6] = (_Float16)((z0b.z + z1b.z + z2b.z + z3b.z) * 0.25f);
  mu[7] = (_Float16)((z0b.w + z1b.w + z2b.w + z3b.w) * 0.25f);
  mx[0] = (_Float16)fmaxf(fmaxf(z0a.x, z1a.x), fmaxf(z2a.x, z3a.x));
  mx[1] = (_Float16)fmaxf(fmaxf(z0a.y, z1a.y), fmaxf(z2a.y, z3a.y));
  mx[2] = (_Float16)fmaxf(fmaxf(z0a.z, z1a.z), fmaxf(z2a.z, z3a.z));
  mx[3] = (_Float16)fmaxf(fmaxf(z0a.w, z1a.w), fmaxf(z2a.w, z3a.w));
  mx[4] = (_Float16)fmaxf(fmaxf(z0b.x, z1b.x), fmaxf(z2b.x, z3b.x));
  mx[5] = (_Float16)fmaxf(fmaxf(z0b.y, z1b.y), fmaxf(z2b.y, z3b.y));
  mx[6] = (_Float16)fmaxf(fmaxf(z0b.z, z1b.z), fmaxf(z2b.z, z3b.z));
  mx[7] = (_Float16)fmaxf(fmaxf(z0b.w, z1b.w), fmaxf(z2b.w, z3b.w));
  *reinterpret_cast<f16x8*>(&h0[(size_t)row * HID + c]) = mu;
  *reinterpret_cast<f16x8*>(&h0[(size_t)row * HID + DIM + c]) = mx;
}

// ---------------- f16 MFMA GEMM (double-buffered): out16 = act(A @ W^T + bias) ----------------
__global__ __launch_bounds__(256, 2) void gemm_mfma_kernel(const _Float16* __restrict__ A,
                                                           const _Float16* __restrict__ W,
                                                           const float* __restrict__ bias,
                                                           _Float16* __restrict__ out16,
                                                           int act) {
  __shared__ __align__(16) char smem[32768];  // 2 buffers x (A 8K + B 8K)
  const int tid = threadIdx.x;
  const int lane = tid & 63;
  const int w = tid >> 6;
  const int wm = w >> 1, wn = w & 1;
  const int row0 = blockIdx.x * 128;
  const int col0 = blockIdx.y * 128;

  int a_off[4], b_off[4];
#pragma unroll
  for (int m = 0; m < 4; ++m) {
    int r = wm * 64 + m * 16 + (lane & 15);
    a_off[m] = r * 64 + (((lane >> 4) ^ S_SWZ(r)) * 16);
  }
#pragma unroll
  for (int n = 0; n < 4; ++n) {
    int r = wn * 64 + n * 16 + (lane & 15);
    b_off[n] = r * 64 + (((lane >> 4) ^ S_SWZ(r)) * 16);
  }

  int goff[2], wb[2];
#pragma unroll
  for (int h = 0; h < 2; ++h) {
    int i = h * 256 + tid;
    int r = i >> 2, cs = i & 3;
    int c = cs ^ S_SWZ(r);
    goff[h] = r * HID + c * 8;
    wb[h] = h * 4096 + w * 1024;
  }

  const _Float16* arow = A + (size_t)row0 * HID;
  const _Float16* brow = W + (size_t)col0 * HID;

  f32x4 acc[4][4];
#pragma unroll
  for (int m = 0; m < 4; ++m)
#pragma unroll
    for (int n = 0; n < 4; ++n) acc[m][n] = (f32x4)0.0f;

  auto stage = [&](int b, int kt) {
#pragma unroll
    for (int h = 0; h < 2; ++h) {
      int go = goff[h] + kt * 32;
      gload_lds16(arow + go, smem + b * 16384 + wb[h]);
      gload_lds16(brow + go, smem + b * 16384 + 8192 + wb[h]);
    }
  };
  auto compute = [&](int b) {
    f16x8 bf[4];
#pragma unroll
    for (int n = 0; n < 4; ++n) bf[n] = *(const f16x8*)(smem + b * 16384 + 8192 + b_off[n]);
#pragma unroll
    for (int m = 0; m < 4; ++m) {
      f16x8 af = *(const f16x8*)(smem + b * 16384 + a_off[m]);
#pragma unroll
      for (int n = 0; n < 4; ++n)
        acc[m][n] = __builtin_amdgcn_mfma_f32_16x16x32_f16(af, bf[n], acc[m][n], 0, 0, 0);
    }
  };

  stage(0, 0);
  __syncthreads();
#pragma unroll 1
  for (int k = 0; k < 16; ++k) {
    stage(1, 2 * k + 1);
    compute(0);
    __syncthreads();
    if (k < 15) stage(0, 2 * k + 2);
    compute(1);
    __syncthreads();
  }

  float bv[4];
#pragma unroll
  for (int n = 0; n < 4; ++n) bv[n] = bias[col0 + wn * 64 + n * 16 + (lane & 15)];

#pragma unroll
  for (int m = 0; m < 4; ++m)
#pragma unroll
    for (int n = 0; n < 4; ++n) {
      int cl = col0 + wn * 64 + n * 16 + (lane & 15);
#pragma unroll
      for (int j = 0; j < 4; ++j) {
        int rl = row0 + wm * 64 + m * 16 + ((lane >> 4) << 2) + j;
        float v = acc[m][n][j] + bv[n];
        if (act && v < 0.0f) v *= 0.01f;
        out16[(size_t)rl * HID + cl] = (_Float16)v;
      }
    }
}

// ---------------- final elementwise + entropy partial sums (h2 in f16) ----------------
__global__ __launch_bounds__(256) void outgen_kernel(const float* __restrict__ x,
                                                     const _Float16* __restrict__ h2,
                                                     const float* __restrict__ eps,
                                                     float* __restrict__ xout,
                                                     float* __restrict__ partials) {
  int tid = threadIdx.x;
  int gid = blockIdx.x * 256 + tid;
  size_t base = (size_t)gid * 4;
  int i = (int)(base >> 9);
  int c = (int)(base & 511);
  float4 xv = *reinterpret_cast<const float4*>(&x[base]);
  float4 ev = *reinterpret_cast<const float4*>(&eps[base]);
  f16x4 muh = *reinterpret_cast<const f16x4*>(&h2[(size_t)i * HID + c]);
  f16x4 hsh = *reinterpret_cast<const f16x4*>(&h2[(size_t)i * HID + DIM + c]);
  float hs0 = (float)hsh[0], hs1 = (float)hsh[1], hs2 = (float)hsh[2], hs3 = (float)hsh[3];
  float4 xo;
  xo.x = xv.x + (float)muh[0] + expf(0.5f * hs0) * ev.x;
  xo.y = xv.y + (float)muh[1] + expf(0.5f * hs1) * ev.y;
  xo.z = xv.z + (float)muh[2] + expf(0.5f * hs2) * ev.z;
  xo.w = xv.w + (float)muh[3] + expf(0.5f * hs3) * ev.w;
  *reinterpret_cast<float4*>(&xout[base]) = xo;
  float lsum = hs0 + hs1 + hs2 + hs3;
  for (int off = 32; off > 0; off >>= 1) lsum += __shfl_down(lsum, off);
  __shared__ float red[4];
  if ((tid & 63) == 0) red[tid >> 6] = lsum;
  __syncthreads();
  if (tid == 0) partials[blockIdx.x] = red[0] + red[1] + red[2] + red[3];
}

__global__ __launch_bounds__(256) void entfin_kernel(const float* __restrict__ partials,
                                                     float* __restrict__ ent) {
  int t = threadIdx.x;
  float s = 0.0f;
  for (int q = 0; q < 16; ++q) s += partials[t + 256 * q];
  for (int off = 32; off > 0; off >>= 1) s += __shfl_down(s, off);
  __shared__ float red[4];
  if ((t & 63) == 0) red[t >> 6] = s;
  __syncthreads();
  if (t == 0)
    ent[0] = 0.5f + 0.9189385332046727f +
             0.5f * (red[0] + red[1] + red[2] + red[3]) / (8192.0f * 512.0f);
}

extern "C" void kernel_launch(void* const* d_in, const int* in_sizes, int n_in,
                              void* d_out, int out_size, void* d_ws, size_t ws_size,
                              hipStream_t stream) {
  const float* x = (const float*)d_in[0];
  const float* W1 = (const float*)d_in[1];
  const float* b1 = (const float*)d_in[2];
  const float* W2 = (const float*)d_in[3];
  const float* b2 = (const float*)d_in[4];
  const float* eps = (const float*)d_in[5];

  float* out = (float*)d_out;
  float* ws = (float*)d_ws;

  // workspace layout (float offsets)
  float* sq = ws;                                   // [0, 8192)
  float* partials = ws + 40960;                     // [40960, 45056)
  unsigned int* cand = (unsigned int*)(ws + 65536); // 8192*256 u32 = 8MB (dead after rescore)
  _Float16* h2f = (_Float16*)(ws + 65536);          // 8192*1024 halves, overlaps cand
  _Float16* xh = (_Float16*)(ws + 8454144);         // 8192*512 halves (dead after dist)
  _Float16* h0f = (_Float16*)(ws + 8454144);        // 8192*1024 halves, overlaps xh
  _Float16* h1f = (_Float16*)(ws + 12648448);       // 8192*1024 halves
  _Float16* W1f = (_Float16*)(ws + 16842752);       // 1024*1024 halves
  _Float16* W2f = (_Float16*)(ws + 17367040);       // 1024*1024 halves

  float* xout = out;
  float* ent = out + (size_t)N_ROWS * DIM;
  float* orows = ent + 1;
  float* osubs = orows + (size_t)N_ROWS * 4;

  convert_kernel<<<6144, 256, 0, stream>>>(x, W1, W2, xh, W1f, W2f, sq);
  dist_cand_mfma<<<dim3(64, NSPLIT), 256, 0, stream>>>(xh, sq, cand);
  rescore_pool_kernel<<<N_ROWS, 64, 0, stream>>>(x, sq, cand, orows, osubs, h0f);
  gemm_mfma_kernel<<<dim3(64, 8), 256, 0, stream>>>(h0f, W1f, b1, h1f, 1);
  gemm_mfma_kernel<<<dim3(64, 8), 256, 0, stream>>>(h1f, W2f, b2, h2f, 0);
  outgen_kernel<<<4096, 256, 0, stream>>>(x, h2f, eps, xout, partials);
  entfin_kernel<<<1, 256, 0, stream>>>(partials, ent);
}